// Round 1
// baseline (22188.939 us; speedup 1.0000x reference)
//
#include <hip/hip_runtime.h>
#include <math.h>
#include <stdint.h>

#define LL 2
#define HH 4
#define DHH 64
#define DD 256
#define BB 8
#define NI 8192
#define ND 4096
#define NHOM 12288
#define KPOOL 768
#define EC 65536
#define EI 32768
#define EO 32768
#define EK 8192
#define EHGT (EC+EI+EO+EK)
#define EHOM (EC+EI+EO+EK+NHOM)
#define ENC_NEG_INF 0x007FFFFFu

__device__ inline float gelu_f(float x){ return 0.5f*x*(1.f+erff(x*0.70710678118654752f)); }
__device__ inline uint32_t fenc(float x){ uint32_t u=__float_as_uint(x); return (u&0x80000000u)? ~u : (u|0x80000000u); }
__device__ inline float fdec(uint32_t k){ return (k&0x80000000u)? __uint_as_float(k&0x7fffffffu) : __uint_as_float(~k); }

// ---------------- generic fill ----------------
__global__ void fill_u32(uint32_t* p, uint32_t v, int n){
    int i = blockIdx.x*256 + threadIdx.x;
    if(i<n) p[i]=v;
}

// ---------------- GEMM: C[M,N] = (gelu?)A[M,K] @ B[K,N]; M%64==0,N%64==0,K%16==0 -----
template<bool GELU_A>
__global__ __launch_bounds__(256) void gemm64(const float* __restrict__ A, const float* __restrict__ B,
                                              float* __restrict__ C, int M, int N, int K){
    __shared__ float As[16][65];
    __shared__ float Bs[16][65];
    int tid = threadIdx.x;
    int tx = tid & 15, ty = tid >> 4;
    int m0 = blockIdx.y*64, n0 = blockIdx.x*64;
    float acc[4][4] = {};
    for(int k0=0;k0<K;k0+=16){
        for(int t=tid;t<1024;t+=256){
            int m=t>>4, kk=t&15;
            float a = A[(size_t)(m0+m)*K + k0+kk];
            if(GELU_A) a = gelu_f(a);
            As[kk][m] = a;
        }
        for(int t=tid;t<1024;t+=256){
            int kk=t>>6, n=t&63;
            Bs[kk][n] = B[(size_t)(k0+kk)*N + n0+n];
        }
        __syncthreads();
        #pragma unroll
        for(int kk=0;kk<16;kk++){
            float av[4], bv[4];
            #pragma unroll
            for(int i=0;i<4;i++) av[i]=As[kk][ty*4+i];
            #pragma unroll
            for(int j=0;j<4;j++) bv[j]=Bs[kk][tx*4+j];
            #pragma unroll
            for(int i=0;i<4;i++)
                #pragma unroll
                for(int j=0;j<4;j++) acc[i][j] += av[i]*bv[j];
        }
        __syncthreads();
    }
    for(int i=0;i<4;i++)
        for(int j=0;j<4;j++)
            C[(size_t)(m0+ty*4+i)*N + n0+tx*4+j] = acc[i][j];
}

// ---------- combine: out[d, h*64+f] = sum_k W[d, h*64+k] * R[h,k,f] ----------
__global__ void combine_w(const float* __restrict__ W, const float* __restrict__ R,
                          float* __restrict__ out){
    int d = blockIdx.x;
    int c = threadIdx.x;
    int h = c >> 6, f = c & 63;
    const float* Wrow = W + d*DD + h*64;
    const float* Rh = R + h*4096 + f;
    float s = 0.f;
    #pragma unroll 8
    for(int k=0;k<64;k++) s += Wrow[k]*Rh[k*64];
    out[d*DD + c] = s;
}

// ---------------- HGT edge passes ----------------
__global__ void hgt_pass1(const int* __restrict__ row, const int* __restrict__ col, int E,
                          const float* __restrict__ Q, const float* __restrict__ KA,
                          const float* __restrict__ prel, float* __restrict__ sc,
                          uint32_t* __restrict__ mx){
    int i = blockIdx.x*256 + threadIdx.x;
    if(i >= E*HH) return;
    int e = i >> 2, h = i & 3;
    int rn = row[e], cn = col[e];
    const float* q  = Q  + (size_t)cn*DD + h*64;
    const float* ka = KA + (size_t)rn*DD + h*64;
    float s = 0.f;
    #pragma unroll 8
    for(int d=0;d<64;d++) s += q[d]*ka[d];
    s *= prel[h]*0.125f;
    sc[i] = s;
    atomicMax(&mx[cn*HH + h], fenc(s));
}

__global__ void hgt_pass2(const int* __restrict__ col, int E, float* __restrict__ sc,
                          const uint32_t* __restrict__ mx, float* __restrict__ den){
    int i = blockIdx.x*256 + threadIdx.x;
    if(i >= E*HH) return;
    int e = i >> 2, h = i & 3;
    int cn = col[e];
    float a = expf(sc[i] - fdec(mx[cn*HH + h]));
    sc[i] = a;
    atomicAdd(&den[cn*HH + h], a);
}

__global__ void hgt_pass3(const int* __restrict__ row, const int* __restrict__ col, int E,
                          const float* __restrict__ sc, const float* __restrict__ den,
                          const float* __restrict__ VM, float* __restrict__ agg){
    int i = blockIdx.x*256 + threadIdx.x;
    if(i >= E*HH) return;
    int e = i >> 2, h = i & 3;
    int rn = row[e], cn = col[e];
    float alpha = sc[i] / (den[cn*HH + h] + 1e-16f);
    const float* vm = VM + (size_t)rn*DD + h*64;
    float* ag = agg + (size_t)cn*DD + h*64;
    #pragma unroll 8
    for(int d=0;d<64;d++) atomicAdd(&ag[d], alpha*vm[d]);
}

// epilogue: val = sig(skip[t])*o + (1-sig)*x ; mode0: xacc=0.5*val ; mode1: xnext=relu(xacc+0.5*val)
__global__ void hgt_epilogue(const float* __restrict__ o, const float* __restrict__ x,
                             const float* __restrict__ skip, int t, int n,
                             float* __restrict__ xacc, float* __restrict__ xnext, int mode){
    int i = blockIdx.x*256 + threadIdx.x;
    if(i >= n*DD) return;
    float g = 1.f/(1.f + expf(-skip[t]));
    float val = g*o[i] + (1.f-g)*x[i];
    if(mode==0){
        xacc[i] = 0.5f*val;
    } else {
        float v2 = xacc[i] + 0.5f*val;
        xnext[i] = v2 > 0.f ? v2 : 0.f;
    }
}

// ---------------- pooling ----------------
__global__ void pool_h(const float* __restrict__ x, const float* __restrict__ w,
                       float* __restrict__ h, int n){
    int node = blockIdx.x*4 + (threadIdx.x>>6);
    int lane = threadIdx.x & 63;
    if(node >= n) return;
    const float* xr = x + (size_t)node*DD;
    float s = 0.f;
    for(int j=lane;j<DD;j+=64) s += xr[j]*w[j];
    for(int m=32;m;m>>=1) s += __shfl_xor(s, m);
    if(lane==0) h[node] = s;
}

__global__ void add_off(const int* __restrict__ src, int n, int off, int* __restrict__ dst){
    int i = blockIdx.x*256 + threadIdx.x;
    if(i<n) dst[i] = src[i] + off;
}
__global__ void iota2(int* __restrict__ a, int* __restrict__ b, int n){
    int i = blockIdx.x*256 + threadIdx.x;
    if(i<n){ a[i]=i; b[i]=i; }
}

__global__ void pool_pass1(const int* __restrict__ row, const int* __restrict__ col, int E,
                           const float* __restrict__ h, const float* __restrict__ att,
                           float* __restrict__ esc, uint32_t* __restrict__ mx){
    int i = blockIdx.x*256 + threadIdx.x;
    if(i>=E) return;
    float e = att[0]*h[row[i]] + att[1]*h[col[i]];
    e = e >= 0.f ? e : 0.2f*e;
    esc[i] = e;
    atomicMax(&mx[col[i]], fenc(e));
}
__global__ void pool_pass2(const int* __restrict__ col, int E, float* __restrict__ esc,
                           const uint32_t* __restrict__ mx, float* __restrict__ den){
    int i = blockIdx.x*256 + threadIdx.x;
    if(i>=E) return;
    float a = expf(esc[i] - fdec(mx[col[i]]));
    esc[i] = a;
    atomicAdd(&den[col[i]], a);
}
__global__ void pool_pass3(const int* __restrict__ row, const int* __restrict__ col, int E,
                           const float* __restrict__ esc, const float* __restrict__ den,
                           const float* __restrict__ h, float* __restrict__ score){
    int i = blockIdx.x*256 + threadIdx.x;
    if(i>=E) return;
    atomicAdd(&score[col[i]], esc[i]/(den[col[i]]+1e-16f) * h[row[i]]);
}

// top-768 of 1536 per graph via bitonic sort (pad to 2048)
__global__ __launch_bounds__(512) void topk_kernel(const float* __restrict__ score,
                                                   const float* __restrict__ bias,
                                                   int* __restrict__ sel_node,
                                                   float* __restrict__ sel_scale){
    __shared__ float skey[2048];
    __shared__ int   sval[2048];
    int b = blockIdx.x;
    float bv = bias[0];
    for(int p=threadIdx.x;p<2048;p+=512){
        if(p<1536){
            int node = (p<1024) ? (b*1024 + p) : (NI + b*512 + (p-1024));
            skey[p] = score[node] + bv;
            sval[p] = node;
        } else {
            skey[p] = -INFINITY;
            sval[p] = -1;
        }
    }
    for(int k=2;k<=2048;k<<=1){
        for(int j=k>>1;j>0;j>>=1){
            __syncthreads();
            for(int i=threadIdx.x;i<2048;i+=512){
                int ixj = i^j;
                if(ixj > i){
                    bool up = ((i & k) == 0);
                    float ki = skey[i], kj = skey[ixj];
                    if((ki < kj) == up){
                        skey[i]=kj; skey[ixj]=ki;
                        int t=sval[i]; sval[i]=sval[ixj]; sval[ixj]=t;
                    }
                }
            }
        }
    }
    __syncthreads();
    for(int j=threadIdx.x;j<KPOOL;j+=512){
        sel_node[b*KPOOL + j] = sval[j];
        sel_scale[b*KPOOL + j] = tanhf(skey[j]);
    }
}

__global__ void gather_xp(const int* __restrict__ sel, const float* __restrict__ scale,
                          const float* __restrict__ xi, const float* __restrict__ xd,
                          float* __restrict__ xp){
    int i = blockIdx.x*256 + threadIdx.x;   // grid = B*KPOOL blocks of 256
    int rowp = i >> 8, c = i & 255;
    int node = sel[rowp];
    float s = scale[rowp];
    float v = (node < NI) ? xi[(size_t)node*DD + c] : xd[(size_t)(node-NI)*DD + c];
    xp[i] = v*s;
}

// ---------------- transformer attention: wave per (b,h,qrow) ----------------
__global__ __launch_bounds__(256) void attn_kernel(const float* __restrict__ Qb,
                                                   const float* __restrict__ Kb,
                                                   const float* __restrict__ Vb,
                                                   float* __restrict__ Ob){
    __shared__ float qs[4][64];
    __shared__ float pbuf[4][KPOOL];
    int w = threadIdx.x >> 6, lane = threadIdx.x & 63;
    int g = blockIdx.x*4 + w;                 // 0 .. B*HH*KPOOL-1
    int b = g / (HH*KPOOL);
    int rem = g - b*(HH*KPOOL);
    int h = rem / KPOOL;
    int q = rem - h*KPOOL;
    const float* qv = Qb + ((size_t)(b*KPOOL + q))*DD + h*64;
    qs[w][lane] = qv[lane];
    __syncthreads();
    float s_loc[KPOOL/64];
    float lmax = -INFINITY;
    #pragma unroll
    for(int jj=0;jj<KPOOL/64;jj++){
        int j = lane + jj*64;
        const float* kr = Kb + ((size_t)(b*KPOOL + j))*DD + h*64;
        float s = 0.f;
        #pragma unroll 8
        for(int d=0;d<64;d++) s += qs[w][d]*kr[d];
        s *= 0.125f;
        s_loc[jj] = s;
        lmax = fmaxf(lmax, s);
    }
    for(int m=32;m;m>>=1) lmax = fmaxf(lmax, __shfl_xor(lmax, m));
    float lden = 0.f;
    #pragma unroll
    for(int jj=0;jj<KPOOL/64;jj++){
        float pv = expf(s_loc[jj] - lmax);
        pbuf[w][lane + jj*64] = pv;
        lden += pv;
    }
    for(int m=32;m;m>>=1) lden += __shfl_xor(lden, m);
    float inv = 1.f/lden;
    __syncthreads();
    float o = 0.f;
    for(int j=0;j<KPOOL;j++){
        o += pbuf[w][j] * Vb[((size_t)(b*KPOOL + j))*DD + h*64 + lane];
    }
    Ob[((size_t)(b*KPOOL + q))*DD + h*64 + lane] = o*inv;
}

// layernorm row kernel: y = xp + o2 ; gatt = g*(y-mu)/sqrt(var+eps)+b
__global__ __launch_bounds__(256) void ln_kernel(const float* __restrict__ xp, const float* __restrict__ o2,
                                                 const float* __restrict__ lg, const float* __restrict__ lb,
                                                 float* __restrict__ gatt){
    __shared__ float red[256];
    int r = blockIdx.x, c = threadIdx.x;
    float y = xp[(size_t)r*DD + c] + o2[(size_t)r*DD + c];
    red[c] = y; __syncthreads();
    for(int s=128;s;s>>=1){ if(c<s) red[c] += red[c+s]; __syncthreads(); }
    float mu = red[0]*(1.f/DD);
    __syncthreads();
    float d = y - mu;
    red[c] = d*d; __syncthreads();
    for(int s=128;s;s>>=1){ if(c<s) red[c] += red[c+s]; __syncthreads(); }
    float var = red[0]*(1.f/DD);
    gatt[(size_t)r*DD + c] = lg[c]*d/sqrtf(var+1e-5f) + lb[c];
}

__global__ void feat_reduce(const float* __restrict__ xp, const float* __restrict__ gatt,
                            float* __restrict__ out){
    int b = blockIdx.x, c = threadIdx.x;
    float s1=0.f, s2=0.f;
    for(int j=0;j<KPOOL;j++){
        s1 += xp[((size_t)(b*KPOOL + j))*DD + c];
        s2 += gatt[((size_t)(b*KPOOL + j))*DD + c];
    }
    out[b*512 + c] = s1;
    out[b*512 + 256 + c] = s2;
}

__global__ void cosine_kernel(const float* __restrict__ u, const float* __restrict__ v,
                              float* __restrict__ out){
    int b = blockIdx.x, t = threadIdx.x;
    float du=0.f, nu=0.f, nv=0.f;
    for(int j=t;j<512;j+=64){
        float a = u[b*512+j], bb = v[b*512+j];
        du += a*bb; nu += a*a; nv += bb*bb;
    }
    for(int m=32;m;m>>=1){
        du += __shfl_xor(du,m); nu += __shfl_xor(nu,m); nv += __shfl_xor(nv,m);
    }
    if(t==0) out[b] = du / (fmaxf(sqrtf(nu),1e-8f)*fmaxf(sqrtf(nv),1e-8f));
}

// =======================================================================
extern "C" void kernel_launch(void* const* d_in, const int* in_sizes, int n_in,
                              void* d_out, int out_size, void* d_ws, size_t ws_size,
                              hipStream_t stream){
    (void)in_sizes; (void)n_in; (void)out_size; (void)ws_size;
    const float* hgt_Wk   = (const float*)d_in[12];
    const float* hgt_Wq   = (const float*)d_in[13];
    const float* hgt_Wv   = (const float*)d_in[14];
    const float* hgt_Wo   = (const float*)d_in[15];
    const float* hgt_arel = (const float*)d_in[16];
    const float* hgt_mrel = (const float*)d_in[17];
    const float* hgt_prel = (const float*)d_in[18];
    const float* hgt_skip = (const float*)d_in[19];
    const float* pool_W   = (const float*)d_in[20];
    const float* pool_att = (const float*)d_in[21];
    const float* pool_bias= (const float*)d_in[22];
    const float* t_wq     = (const float*)d_in[23];
    const float* t_wk     = (const float*)d_in[24];
    const float* t_wv     = (const float*)d_in[25];
    const float* t_wo     = (const float*)d_in[26];
    const float* ln_g     = (const float*)d_in[27];
    const float* ln_b     = (const float*)d_in[28];
    float* out = (float*)d_out;

    char* base = (char*)d_ws;
    size_t off = 0;
    auto alloc = [&](size_t nElems)->void*{
        void* p = (void*)(base + off);
        off += ((nElems*4 + 255) & ~(size_t)255);
        return p;
    };
    // persistent
    float* wtk  = (float*)alloc(16*65536);
    float* wtv  = (float*)alloc(16*65536);
    float* ubuf = (float*)alloc(BB*512);
    float* vbuf = (float*)alloc(BB*512);
    float* xa_i = (float*)alloc((size_t)NI*DD);
    float* xa_d = (float*)alloc((size_t)ND*DD);
    float* xb_i = (float*)alloc((size_t)NI*DD);
    float* xb_d = (float*)alloc((size_t)ND*DD);
    size_t region = off;
    // conv scratch
    float* q_i  = (float*)alloc((size_t)NI*DD);
    float* q_d  = (float*)alloc((size_t)ND*DD);
    float* ka   = (float*)alloc((size_t)NI*DD);
    float* vm[4];
    for(int r=0;r<4;r++) vm[r] = (float*)alloc((size_t)NI*DD);
    float* scb  = (float*)alloc((size_t)EHGT*HH);
    uint32_t* mk_i = (uint32_t*)alloc((size_t)NI*HH);
    uint32_t* mk_d = (uint32_t*)alloc((size_t)ND*HH);
    float* den_i = (float*)alloc((size_t)NI*HH);
    float* den_d = (float*)alloc((size_t)ND*HH);
    float* agg_i = (float*)alloc((size_t)NI*DD);
    float* agg_d = (float*)alloc((size_t)ND*DD);
    float* ob_i  = (float*)alloc((size_t)NI*DD);
    float* ob_d  = (float*)alloc((size_t)ND*DD);
    float* xacc_i= (float*)alloc((size_t)NI*DD);
    float* xacc_d= (float*)alloc((size_t)ND*DD);
    size_t conv_end = off;
    // pooling + transformer scratch overlays conv scratch
    off = region;
    float* hvec = (float*)alloc(NHOM);
    int* erow   = (int*)alloc(EHOM);
    int* ecol   = (int*)alloc(EHOM);
    float* esc  = (float*)alloc(EHOM);
    uint32_t* pmk = (uint32_t*)alloc(NHOM);
    float* pden = (float*)alloc(NHOM);
    float* pscore = (float*)alloc(NHOM);
    int* seln   = (int*)alloc(BB*KPOOL);
    float* sels = (float*)alloc(BB*KPOOL);
    float* xp   = (float*)alloc((size_t)BB*KPOOL*DD);
    float* qb   = (float*)alloc((size_t)BB*KPOOL*DD);
    float* kb   = (float*)alloc((size_t)BB*KPOOL*DD);
    float* vb   = (float*)alloc((size_t)BB*KPOOL*DD);
    float* ao   = (float*)alloc((size_t)BB*KPOOL*DD);
    float* o2   = (float*)alloc((size_t)BB*KPOOL*DD);
    float* gatt = (float*)alloc((size_t)BB*KPOOL*DD);
    (void)conv_end;

    const int st_tab[2][4] = {{0,1,0,0},{0,0,1,0}};
    const int dt_tab[2][4] = {{0,0,1,0},{0,1,0,0}};
    const int Erel[4] = {EC, EI, EO, EK};
    const size_t scoff[4] = {0, (size_t)EC*HH, (size_t)(EC+EI)*HH, (size_t)(EC+EI+EO)*HH};

    // -------- phase 0: fold arel/mrel into Wk/Wv per (l,dir,rel) --------
    for(int l=0;l<LL;l++) for(int dir=0;dir<2;dir++) for(int r=0;r<4;r++){
        int wb = l*2 + dir;
        int idx = wb*4 + r;
        const float* Wk = hgt_Wk + (size_t)(wb*2 + st_tab[dir][r])*65536;
        const float* Wv = hgt_Wv + (size_t)(wb*2 + st_tab[dir][r])*65536;
        const float* Ra = hgt_arel + (size_t)idx*HH*DHH*DHH;
        const float* Rm = hgt_mrel + (size_t)idx*HH*DHH*DHH;
        combine_w<<<256,256,0,stream>>>(Wk, Ra, wtk + (size_t)idx*65536);
        combine_w<<<256,256,0,stream>>>(Wv, Rm, wtv + (size_t)idx*65536);
    }

    // -------- per-branch pipeline --------
    for(int bi=0;bi<2;bi++){
        int ib = bi*6;
        const float* x_inst = (const float*)d_in[ib+0];
        const float* x_data = (const float*)d_in[ib+1];
        const int* ecp = (const int*)d_in[ib+2];
        const int* eip = (const int*)d_in[ib+3];
        const int* eop = (const int*)d_in[ib+4];
        const int* ekp = (const int*)d_in[ib+5];
        const int* rows_f[4] = {ecp, eip, eop, ekp};
        const int* cols_f[4] = {ecp+EC, eip+EI, eop+EO, ekp+EK};
        const int* rows_r[4] = {ecp+EC, eip+EI, eop+EO, ekp+EK};
        const int* cols_r[4] = {ecp, eip, eop, ekp};

        const float* cur_i = x_inst;
        const float* cur_d = x_data;
        for(int l=0;l<LL;l++){
            float* nxt_i = (l==0) ? xa_i : xb_i;
            float* nxt_d = (l==0) ? xa_d : xb_d;
            for(int dir=0;dir<2;dir++){
                int wb = l*2 + dir;
                const int** rows = dir ? rows_r : rows_f;
                const int** cols = dir ? cols_r : cols_f;
                // Q per node type
                gemm64<false><<<dim3(DD/64, NI/64),256,0,stream>>>(cur_i, hgt_Wq + (size_t)(wb*2+0)*65536, q_i, NI, DD, DD);
                gemm64<false><<<dim3(DD/64, ND/64),256,0,stream>>>(cur_d, hgt_Wq + (size_t)(wb*2+1)*65536, q_d, ND, DD, DD);
                // VM per relation
                for(int r=0;r<4;r++){
                    int st = st_tab[dir][r];
                    const float* xs = st ? cur_d : cur_i;
                    int ns = st ? ND : NI;
                    gemm64<false><<<dim3(DD/64, ns/64),256,0,stream>>>(xs, wtv + (size_t)(wb*4+r)*65536, vm[r], ns, DD, DD);
                }
                // init segment-softmax state
                fill_u32<<<(NI*HH+255)/256,256,0,stream>>>(mk_i, ENC_NEG_INF, NI*HH);
                fill_u32<<<(ND*HH+255)/256,256,0,stream>>>(mk_d, ENC_NEG_INF, ND*HH);
                fill_u32<<<(NI*HH+255)/256,256,0,stream>>>((uint32_t*)den_i, 0u, NI*HH);
                fill_u32<<<(ND*HH+255)/256,256,0,stream>>>((uint32_t*)den_d, 0u, ND*HH);
                fill_u32<<<(NI*DD+255)/256,256,0,stream>>>((uint32_t*)agg_i, 0u, NI*DD);
                fill_u32<<<(ND*DD+255)/256,256,0,stream>>>((uint32_t*)agg_d, 0u, ND*DD);
                // pass 1 (scores + segment max)
                for(int r=0;r<4;r++){
                    int st = st_tab[dir][r], dt = dt_tab[dir][r];
                    const float* xs = st ? cur_d : cur_i;
                    int ns = st ? ND : NI;
                    gemm64<false><<<dim3(DD/64, ns/64),256,0,stream>>>(xs, wtk + (size_t)(wb*4+r)*65536, ka, ns, DD, DD);
                    hgt_pass1<<<(Erel[r]*HH+255)/256,256,0,stream>>>(rows[r], cols[r], Erel[r],
                        dt ? q_d : q_i, ka, hgt_prel + (size_t)(wb*4+r)*HH,
                        scb + scoff[r], dt ? mk_d : mk_i);
                }
                // pass 2 (exp + denom)
                for(int r=0;r<4;r++){
                    int dt = dt_tab[dir][r];
                    hgt_pass2<<<(Erel[r]*HH+255)/256,256,0,stream>>>(cols[r], Erel[r],
                        scb + scoff[r], dt ? mk_d : mk_i, dt ? den_d : den_i);
                }
                // pass 3 (weighted aggregate)
                for(int r=0;r<4;r++){
                    int dt = dt_tab[dir][r];
                    hgt_pass3<<<(Erel[r]*HH+255)/256,256,0,stream>>>(rows[r], cols[r], Erel[r],
                        scb + scoff[r], dt ? den_d : den_i, vm[r], dt ? agg_d : agg_i);
                }
                // output proj + gated skip (+ fwd/rev average, + relu at dir==1)
                gemm64<true><<<dim3(DD/64, NI/64),256,0,stream>>>(agg_i, hgt_Wo + (size_t)(wb*2+0)*65536, ob_i, NI, DD, DD);
                gemm64<true><<<dim3(DD/64, ND/64),256,0,stream>>>(agg_d, hgt_Wo + (size_t)(wb*2+1)*65536, ob_d, ND, DD, DD);
                hgt_epilogue<<<(NI*DD+255)/256,256,0,stream>>>(ob_i, cur_i, hgt_skip + wb*2, 0, NI, xacc_i, nxt_i, dir);
                hgt_epilogue<<<(ND*DD+255)/256,256,0,stream>>>(ob_d, cur_d, hgt_skip + wb*2, 1, ND, xacc_d, nxt_d, dir);
            }
            cur_i = nxt_i;
            cur_d = nxt_d;
        }

        // -------- SAGPooling --------
        pool_h<<<NI/4,256,0,stream>>>(cur_i, pool_W, hvec, NI);
        pool_h<<<ND/4,256,0,stream>>>(cur_d, pool_W, hvec+NI, ND);
        // homogeneous edges: row = [ec0, ei0+NI, eo0, ek0, loops]; col = [ec1, ei1, eo1+NI, ek1, loops]
        add_off<<<(EC+255)/256,256,0,stream>>>(ecp,      EC, 0,  erow);
        add_off<<<(EI+255)/256,256,0,stream>>>(eip,      EI, NI, erow+EC);
        add_off<<<(EO+255)/256,256,0,stream>>>(eop,      EO, 0,  erow+EC+EI);
        add_off<<<(EK+255)/256,256,0,stream>>>(ekp,      EK, 0,  erow+EC+EI+EO);
        add_off<<<(EC+255)/256,256,0,stream>>>(ecp+EC,   EC, 0,  ecol);
        add_off<<<(EI+255)/256,256,0,stream>>>(eip+EI,   EI, 0,  ecol+EC);
        add_off<<<(EO+255)/256,256,0,stream>>>(eop+EO,   EO, NI, ecol+EC+EI);
        add_off<<<(EK+255)/256,256,0,stream>>>(ekp+EK,   EK, 0,  ecol+EC+EI+EO);
        iota2<<<(NHOM+255)/256,256,0,stream>>>(erow+EC+EI+EO+EK, ecol+EC+EI+EO+EK, NHOM);
        fill_u32<<<(NHOM+255)/256,256,0,stream>>>(pmk, ENC_NEG_INF, NHOM);
        fill_u32<<<(NHOM+255)/256,256,0,stream>>>((uint32_t*)pden, 0u, NHOM);
        fill_u32<<<(NHOM+255)/256,256,0,stream>>>((uint32_t*)pscore, 0u, NHOM);
        pool_pass1<<<(EHOM+255)/256,256,0,stream>>>(erow, ecol, EHOM, hvec, pool_att, esc, pmk);
        pool_pass2<<<(EHOM+255)/256,256,0,stream>>>(ecol, EHOM, esc, pmk, pden);
        pool_pass3<<<(EHOM+255)/256,256,0,stream>>>(erow, ecol, EHOM, esc, pden, hvec, pscore);
        topk_kernel<<<BB,512,0,stream>>>(pscore, pool_bias, seln, sels);
        gather_xp<<<BB*KPOOL,256,0,stream>>>(seln, sels, cur_i, cur_d, xp);

        // -------- transformer --------
        int MR = BB*KPOOL;  // 6144
        gemm64<false><<<dim3(DD/64, MR/64),256,0,stream>>>(xp, t_wq, qb, MR, DD, DD);
        gemm64<false><<<dim3(DD/64, MR/64),256,0,stream>>>(xp, t_wk, kb, MR, DD, DD);
        gemm64<false><<<dim3(DD/64, MR/64),256,0,stream>>>(xp, t_wv, vb, MR, DD, DD);
        attn_kernel<<<BB*HH*KPOOL/4,256,0,stream>>>(qb, kb, vb, ao);
        gemm64<false><<<dim3(DD/64, MR/64),256,0,stream>>>(ao, t_wo, o2, MR, DD, DD);
        ln_kernel<<<MR,256,0,stream>>>(xp, o2, ln_g, ln_b, gatt);
        feat_reduce<<<BB,256,0,stream>>>(xp, gatt, bi ? vbuf : ubuf);
    }

    cosine_kernel<<<BB,64,0,stream>>>(ubuf, vbuf, out);
}

// Round 2
// 18680.194 us; speedup vs baseline: 1.1878x; 1.1878x over previous
//
#include <hip/hip_runtime.h>
#include <math.h>
#include <stdint.h>

#define LL 2
#define HH 4
#define DHH 64
#define DD 256
#define BB 8
#define NI 8192
#define ND 4096
#define NHOM 12288
#define KPOOL 768
#define EC 65536
#define EI 32768
#define EO 32768
#define EK 8192
#define EHGT (EC+EI+EO+EK)
#define EHOM (EC+EI+EO+EK+NHOM)
#define ENC_NEG_INF 0x007FFFFFu

#define GBM 128
#define GBN 128
#define GBK 16

__device__ inline float gelu_f(float x){ return 0.5f*x*(1.f+erff(x*0.70710678118654752f)); }
__device__ inline uint32_t fenc(float x){ uint32_t u=__float_as_uint(x); return (u&0x80000000u)? ~u : (u|0x80000000u); }
__device__ inline float fdec(uint32_t k){ return (k&0x80000000u)? __uint_as_float(k&0x7fffffffu) : __uint_as_float(~k); }

// ---------------- generic fill ----------------
__global__ void fill_u32(uint32_t* p, uint32_t v, int n){
    int i = blockIdx.x*256 + threadIdx.x;
    if(i<n) p[i]=v;
}

// ---------------- batched GEMM: C[M,256] = (gelu?)A[M,256] @ B[256,256] ----------------
struct GDesc { const float* A; const float* B; float* C; int mblks; int gelu; };
struct GArgs { GDesc d[12]; int nd; };

__global__ __launch_bounds__(256) void gemm_batch(GArgs ga){
    __shared__ float As[GBK][GBM+4];
    __shared__ float Bs[GBK][GBN+4];
    int mb = blockIdx.x;
    int di = 0;
    while(di < ga.nd-1 && mb >= ga.d[di].mblks){ mb -= ga.d[di].mblks; di++; }
    const float* __restrict__ A = ga.d[di].A;
    const float* __restrict__ B = ga.d[di].B;
    float* __restrict__ C = ga.d[di].C;
    const int gelu = ga.d[di].gelu;
    const int m0 = mb*GBM, n0 = blockIdx.y*GBN;
    const int tid = threadIdx.x;
    const int tx = tid & 15, ty = tid >> 4;
    const int arow = tid >> 1, acol = (tid & 1)*8;
    const int brow = tid >> 4, bcol = (tid & 15)*8;
    const float* Aptr = A + (size_t)(m0+arow)*DD + acol;
    const float* Bptr = B + (size_t)brow*DD + n0 + bcol;
    float acc[8][8] = {};
    for(int k0=0;k0<DD;k0+=GBK){
        float4 a0 = *(const float4*)(Aptr + k0);
        float4 a1 = *(const float4*)(Aptr + k0 + 4);
        float4 b0 = *(const float4*)(Bptr + (size_t)k0*DD);
        float4 b1 = *(const float4*)(Bptr + (size_t)k0*DD + 4);
        if(gelu){
            a0.x=gelu_f(a0.x); a0.y=gelu_f(a0.y); a0.z=gelu_f(a0.z); a0.w=gelu_f(a0.w);
            a1.x=gelu_f(a1.x); a1.y=gelu_f(a1.y); a1.z=gelu_f(a1.z); a1.w=gelu_f(a1.w);
        }
        __syncthreads();
        As[acol+0][arow]=a0.x; As[acol+1][arow]=a0.y; As[acol+2][arow]=a0.z; As[acol+3][arow]=a0.w;
        As[acol+4][arow]=a1.x; As[acol+5][arow]=a1.y; As[acol+6][arow]=a1.z; As[acol+7][arow]=a1.w;
        *(float4*)&Bs[brow][bcol]   = b0;
        *(float4*)&Bs[brow][bcol+4] = b1;
        __syncthreads();
        #pragma unroll
        for(int kk=0;kk<GBK;kk++){
            float av[8], bv[8];
            *(float4*)&av[0] = *(const float4*)&As[kk][ty*8];
            *(float4*)&av[4] = *(const float4*)&As[kk][ty*8+4];
            *(float4*)&bv[0] = *(const float4*)&Bs[kk][tx*8];
            *(float4*)&bv[4] = *(const float4*)&Bs[kk][tx*8+4];
            #pragma unroll
            for(int i=0;i<8;i++)
                #pragma unroll
                for(int j=0;j<8;j++) acc[i][j] = fmaf(av[i], bv[j], acc[i][j]);
        }
    }
    float* Cp = C + (size_t)(m0+ty*8)*DD + n0 + tx*8;
    #pragma unroll
    for(int i=0;i<8;i++){
        float4 c0 = {acc[i][0],acc[i][1],acc[i][2],acc[i][3]};
        float4 c1 = {acc[i][4],acc[i][5],acc[i][6],acc[i][7]};
        *(float4*)(Cp + (size_t)i*DD)     = c0;
        *(float4*)(Cp + (size_t)i*DD + 4) = c1;
    }
}

// ---------- combine (all 32 (idx,kv) pairs in one launch) ----------
// out[d, h*64+f] = sum_k W[d, h*64+k] * R[h,k,f]
__global__ void combine_all(const float* __restrict__ Wk, const float* __restrict__ Wv,
                            const float* __restrict__ Ra, const float* __restrict__ Rm,
                            float* __restrict__ wtk, float* __restrict__ wtv){
    const int st_tab[2][4] = {{0,1,0,0},{0,0,1,0}};
    int combo = blockIdx.y;             // 0..31
    int idx = combo >> 1, kv = combo & 1;
    int r = idx & 3, wb = idx >> 2, dir = wb & 1;
    int st = st_tab[dir][r];
    const float* W = (kv ? Wv : Wk) + (size_t)(wb*2 + st)*65536;
    const float* R = (kv ? Rm : Ra) + (size_t)idx*16384;
    float* o = (kv ? wtv : wtk) + (size_t)idx*65536;
    int d = blockIdx.x, c = threadIdx.x;
    int h = c >> 6, f = c & 63;
    const float* Wrow = W + d*DD + h*64;
    const float* Rh = R + h*4096 + f;
    float s = 0.f;
    #pragma unroll 8
    for(int k=0;k<64;k++) s += Wrow[k]*Rh[k*64];
    o[d*DD + c] = s;
}

// ---------------- HGT edge passes (merged over 4 relations) ----------------
struct EArgs {
    const int* row[4]; const int* col[4];
    const float* KA[4]; const float* VM[4];
    const float* Q[2];
    uint32_t* mk[2]; float* den[2]; float* agg[2];
    const float* prel;       // base for this (l,dir): prel[r*HH + h]
    float* sc;
    int dt[4];
};

__device__ inline void edge_decode(int e, int& r, int& el){
    if(e < EC){ r=0; el=e; }
    else if(e < EC+EI){ r=1; el=e-EC; }
    else if(e < EC+EI+EO){ r=2; el=e-(EC+EI); }
    else { r=3; el=e-(EC+EI+EO); }
}

__global__ void hgt_pass1(EArgs ea){
    int i = blockIdx.x*256 + threadIdx.x;
    if(i >= EHGT*HH) return;
    int e = i >> 2, h = i & 3;
    int r, el; edge_decode(e, r, el);
    int dt = ea.dt[r];
    int rn = ea.row[r][el], cn = ea.col[r][el];
    const float* q  = ea.Q[dt] + (size_t)cn*DD + h*64;
    const float* ka = ea.KA[r] + (size_t)rn*DD + h*64;
    float s = 0.f;
    #pragma unroll 8
    for(int d=0;d<64;d++) s += q[d]*ka[d];
    s *= ea.prel[r*HH + h]*0.125f;
    ea.sc[i] = s;
    atomicMax(&ea.mk[dt][cn*HH + h], fenc(s));
}

__global__ void hgt_pass2(EArgs ea){
    int i = blockIdx.x*256 + threadIdx.x;
    if(i >= EHGT*HH) return;
    int e = i >> 2, h = i & 3;
    int r, el; edge_decode(e, r, el);
    int dt = ea.dt[r];
    int cn = ea.col[r][el];
    float a = expf(ea.sc[i] - fdec(ea.mk[dt][cn*HH + h]));
    ea.sc[i] = a;
    atomicAdd(&ea.den[dt][cn*HH + h], a);
}

__global__ void hgt_pass3(EArgs ea){
    int i = blockIdx.x*256 + threadIdx.x;
    if(i >= EHGT*HH) return;
    int e = i >> 2, h = i & 3;
    int r, el; edge_decode(e, r, el);
    int dt = ea.dt[r];
    int rn = ea.row[r][el], cn = ea.col[r][el];
    float alpha = ea.sc[i] / (ea.den[dt][cn*HH + h] + 1e-16f);
    const float* vm = ea.VM[r] + (size_t)rn*DD + h*64;
    float* ag = ea.agg[dt] + (size_t)cn*DD + h*64;
    #pragma unroll 8
    for(int d=0;d<64;d++) atomicAdd(&ag[d], alpha*vm[d]);
}

// epilogue: val = sig(skip[t])*o + (1-sig)*x ; mode0: xacc=0.5*val ; mode1: xnext=relu(xacc+0.5*val)
__global__ void hgt_epilogue(const float* __restrict__ o, const float* __restrict__ x,
                             const float* __restrict__ skip, int t, int n,
                             float* __restrict__ xacc, float* __restrict__ xnext, int mode){
    int i = blockIdx.x*256 + threadIdx.x;
    if(i >= n*DD) return;
    float g = 1.f/(1.f + expf(-skip[t]));
    float val = g*o[i] + (1.f-g)*x[i];
    if(mode==0){
        xacc[i] = 0.5f*val;
    } else {
        float v2 = xacc[i] + 0.5f*val;
        xnext[i] = v2 > 0.f ? v2 : 0.f;
    }
}

// ---------------- pooling ----------------
__global__ void pool_h(const float* __restrict__ x, const float* __restrict__ w,
                       float* __restrict__ h, int n){
    int node = blockIdx.x*4 + (threadIdx.x>>6);
    int lane = threadIdx.x & 63;
    if(node >= n) return;
    const float* xr = x + (size_t)node*DD;
    float s = 0.f;
    for(int j=lane;j<DD;j+=64) s += xr[j]*w[j];
    for(int m=32;m;m>>=1) s += __shfl_xor(s, m);
    if(lane==0) h[node] = s;
}

__global__ void build_hom_edges(const int* __restrict__ ec, const int* __restrict__ ei,
                                const int* __restrict__ eo, const int* __restrict__ ek,
                                int* __restrict__ erow, int* __restrict__ ecol){
    int i = blockIdx.x*256 + threadIdx.x;
    if(i >= EHOM) return;
    int r, c;
    if(i < EC){ r = ec[i]; c = ec[i+EC]; }
    else if(i < EC+EI){ int j=i-EC; r = ei[j]+NI; c = ei[j+EI]; }
    else if(i < EC+EI+EO){ int j=i-(EC+EI); r = eo[j]; c = eo[j+EO]+NI; }
    else if(i < EHGT){ int j=i-(EC+EI+EO); r = ek[j]; c = ek[j+EK]; }
    else { int j=i-EHGT; r = j; c = j; }
    erow[i] = r; ecol[i] = c;
}

__global__ void pool_pass1(const int* __restrict__ row, const int* __restrict__ col,
                           const float* __restrict__ h, const float* __restrict__ att,
                           float* __restrict__ esc, uint32_t* __restrict__ mx){
    int i = blockIdx.x*256 + threadIdx.x;
    if(i>=EHOM) return;
    float e = att[0]*h[row[i]] + att[1]*h[col[i]];
    e = e >= 0.f ? e : 0.2f*e;
    esc[i] = e;
    atomicMax(&mx[col[i]], fenc(e));
}
__global__ void pool_pass2(const int* __restrict__ col, float* __restrict__ esc,
                           const uint32_t* __restrict__ mx, float* __restrict__ den){
    int i = blockIdx.x*256 + threadIdx.x;
    if(i>=EHOM) return;
    float a = expf(esc[i] - fdec(mx[col[i]]));
    esc[i] = a;
    atomicAdd(&den[col[i]], a);
}
__global__ void pool_pass3(const int* __restrict__ row, const int* __restrict__ col,
                           const float* __restrict__ esc, const float* __restrict__ den,
                           const float* __restrict__ h, float* __restrict__ score){
    int i = blockIdx.x*256 + threadIdx.x;
    if(i>=EHOM) return;
    atomicAdd(&score[col[i]], esc[i]/(den[col[i]]+1e-16f) * h[row[i]]);
}

// top-768 of 1536 per graph via bitonic sort (pad to 2048)
__global__ __launch_bounds__(512) void topk_kernel(const float* __restrict__ score,
                                                   const float* __restrict__ bias,
                                                   int* __restrict__ sel_node,
                                                   float* __restrict__ sel_scale){
    __shared__ float skey[2048];
    __shared__ int   sval[2048];
    int b = blockIdx.x;
    float bv = bias[0];
    for(int p=threadIdx.x;p<2048;p+=512){
        if(p<1536){
            int node = (p<1024) ? (b*1024 + p) : (NI + b*512 + (p-1024));
            skey[p] = score[node] + bv;
            sval[p] = node;
        } else {
            skey[p] = -INFINITY;
            sval[p] = -1;
        }
    }
    for(int k=2;k<=2048;k<<=1){
        for(int j=k>>1;j>0;j>>=1){
            __syncthreads();
            for(int i=threadIdx.x;i<2048;i+=512){
                int ixj = i^j;
                if(ixj > i){
                    bool up = ((i & k) == 0);
                    float ki = skey[i], kj = skey[ixj];
                    if((ki < kj) == up){
                        skey[i]=kj; skey[ixj]=ki;
                        int t=sval[i]; sval[i]=sval[ixj]; sval[ixj]=t;
                    }
                }
            }
        }
    }
    __syncthreads();
    for(int j=threadIdx.x;j<KPOOL;j+=512){
        sel_node[b*KPOOL + j] = sval[j];
        sel_scale[b*KPOOL + j] = tanhf(skey[j]);
    }
}

__global__ void gather_xp(const int* __restrict__ sel, const float* __restrict__ scale,
                          const float* __restrict__ xi, const float* __restrict__ xd,
                          float* __restrict__ xp){
    int i = blockIdx.x*256 + threadIdx.x;   // grid = B*KPOOL blocks of 256
    int rowp = i >> 8, c = i & 255;
    int node = sel[rowp];
    float s = scale[rowp];
    float v = (node < NI) ? xi[(size_t)node*DD + c] : xd[(size_t)(node-NI)*DD + c];
    xp[i] = v*s;
}

// ---------------- transformer attention: wave per (b,h,qrow) ----------------
__global__ __launch_bounds__(256) void attn_kernel(const float* __restrict__ Qb,
                                                   const float* __restrict__ Kb,
                                                   const float* __restrict__ Vb,
                                                   float* __restrict__ Ob){
    __shared__ float qs[4][64];
    __shared__ float pbuf[4][KPOOL];
    int w = threadIdx.x >> 6, lane = threadIdx.x & 63;
    int g = blockIdx.x*4 + w;                 // 0 .. B*HH*KPOOL-1
    int b = g / (HH*KPOOL);
    int rem = g - b*(HH*KPOOL);
    int h = rem / KPOOL;
    int q = rem - h*KPOOL;
    const float* qv = Qb + ((size_t)(b*KPOOL + q))*DD + h*64;
    qs[w][lane] = qv[lane];
    __syncthreads();
    float s_loc[KPOOL/64];
    float lmax = -INFINITY;
    #pragma unroll
    for(int jj=0;jj<KPOOL/64;jj++){
        int j = lane + jj*64;
        const float* kr = Kb + ((size_t)(b*KPOOL + j))*DD + h*64;
        float s = 0.f;
        #pragma unroll 8
        for(int d=0;d<64;d++) s += qs[w][d]*kr[d];
        s *= 0.125f;
        s_loc[jj] = s;
        lmax = fmaxf(lmax, s);
    }
    for(int m=32;m;m>>=1) lmax = fmaxf(lmax, __shfl_xor(lmax, m));
    float lden = 0.f;
    #pragma unroll
    for(int jj=0;jj<KPOOL/64;jj++){
        float pv = expf(s_loc[jj] - lmax);
        pbuf[w][lane + jj*64] = pv;
        lden += pv;
    }
    for(int m=32;m;m>>=1) lden += __shfl_xor(lden, m);
    float inv = 1.f/lden;
    __syncthreads();
    float o = 0.f;
    for(int j=0;j<KPOOL;j++){
        o += pbuf[w][j] * Vb[((size_t)(b*KPOOL + j))*DD + h*64 + lane];
    }
    Ob[((size_t)(b*KPOOL + q))*DD + h*64 + lane] = o*inv;
}

// layernorm row kernel: y = xp + o2 ; gatt = g*(y-mu)/sqrt(var+eps)+b
__global__ __launch_bounds__(256) void ln_kernel(const float* __restrict__ xp, const float* __restrict__ o2,
                                                 const float* __restrict__ lg, const float* __restrict__ lb,
                                                 float* __restrict__ gatt){
    __shared__ float red[256];
    int r = blockIdx.x, c = threadIdx.x;
    float y = xp[(size_t)r*DD + c] + o2[(size_t)r*DD + c];
    red[c] = y; __syncthreads();
    for(int s=128;s;s>>=1){ if(c<s) red[c] += red[c+s]; __syncthreads(); }
    float mu = red[0]*(1.f/DD);
    __syncthreads();
    float d = y - mu;
    red[c] = d*d; __syncthreads();
    for(int s=128;s;s>>=1){ if(c<s) red[c] += red[c+s]; __syncthreads(); }
    float var = red[0]*(1.f/DD);
    gatt[(size_t)r*DD + c] = lg[c]*d/sqrtf(var+1e-5f) + lb[c];
}

__global__ void feat_reduce2(const float* __restrict__ xp, const float* __restrict__ gatt,
                             float* __restrict__ out){
    int b = blockIdx.x, c = threadIdx.x;
    int j0 = blockIdx.y*64;
    float s1=0.f, s2=0.f;
    for(int j=j0;j<j0+64;j++){
        size_t base = ((size_t)(b*KPOOL + j))*DD + c;
        s1 += xp[base];
        s2 += gatt[base];
    }
    atomicAdd(&out[b*512 + c], s1);
    atomicAdd(&out[b*512 + 256 + c], s2);
}

__global__ void cosine_kernel(const float* __restrict__ u, const float* __restrict__ v,
                              float* __restrict__ out){
    int b = blockIdx.x, t = threadIdx.x;
    float du=0.f, nu=0.f, nv=0.f;
    for(int j=t;j<512;j+=64){
        float a = u[b*512+j], bb = v[b*512+j];
        du += a*bb; nu += a*a; nv += bb*bb;
    }
    for(int m=32;m;m>>=1){
        du += __shfl_xor(du,m); nu += __shfl_xor(nu,m); nv += __shfl_xor(nv,m);
    }
    if(t==0) out[b] = du / (fmaxf(sqrtf(nu),1e-8f)*fmaxf(sqrtf(nv),1e-8f));
}

// =======================================================================
extern "C" void kernel_launch(void* const* d_in, const int* in_sizes, int n_in,
                              void* d_out, int out_size, void* d_ws, size_t ws_size,
                              hipStream_t stream){
    (void)in_sizes; (void)n_in; (void)out_size; (void)ws_size;
    const float* hgt_Wk   = (const float*)d_in[12];
    const float* hgt_Wq   = (const float*)d_in[13];
    const float* hgt_Wv   = (const float*)d_in[14];
    const float* hgt_Wo   = (const float*)d_in[15];
    const float* hgt_arel = (const float*)d_in[16];
    const float* hgt_mrel = (const float*)d_in[17];
    const float* hgt_prel = (const float*)d_in[18];
    const float* hgt_skip = (const float*)d_in[19];
    const float* pool_W   = (const float*)d_in[20];
    const float* pool_att = (const float*)d_in[21];
    const float* pool_bias= (const float*)d_in[22];
    const float* t_wq     = (const float*)d_in[23];
    const float* t_wk     = (const float*)d_in[24];
    const float* t_wv     = (const float*)d_in[25];
    const float* t_wo     = (const float*)d_in[26];
    const float* ln_g     = (const float*)d_in[27];
    const float* ln_b     = (const float*)d_in[28];
    float* out = (float*)d_out;

    char* base = (char*)d_ws;
    size_t off = 0;
    auto alloc = [&](size_t nElems)->void*{
        void* p = (void*)(base + off);
        off += ((nElems*4 + 255) & ~(size_t)255);
        return p;
    };
    // persistent
    float* wtk  = (float*)alloc(16*65536);
    float* wtv  = (float*)alloc(16*65536);
    float* ubuf = (float*)alloc(BB*512);     // ubuf,vbuf contiguous (one zero fill)
    float* vbuf = (float*)alloc(BB*512);
    float* xa_i = (float*)alloc((size_t)NI*DD);
    float* xa_d = (float*)alloc((size_t)ND*DD);
    float* xb_i = (float*)alloc((size_t)NI*DD);
    float* xb_d = (float*)alloc((size_t)ND*DD);
    size_t region = off;
    // conv scratch
    float* q_i  = (float*)alloc((size_t)NI*DD);   // also reused as ob_i
    float* q_d  = (float*)alloc((size_t)ND*DD);   // also reused as ob_d
    float* ka4  = (float*)alloc((size_t)4*NI*DD);
    float* vmb  = (float*)alloc((size_t)4*NI*DD);
    float* scb  = (float*)alloc((size_t)EHGT*HH);
    uint32_t* mk_i = (uint32_t*)alloc((size_t)NI*HH);   // mk_i,mk_d contiguous
    uint32_t* mk_d = (uint32_t*)alloc((size_t)ND*HH);
    float* den_i = (float*)alloc((size_t)NI*HH);        // den..agg contiguous zero region
    float* den_d = (float*)alloc((size_t)ND*HH);
    float* agg_i = (float*)alloc((size_t)NI*DD);
    float* agg_d = (float*)alloc((size_t)ND*DD);
    float* xacc_i= (float*)alloc((size_t)NI*DD);
    float* xacc_d= (float*)alloc((size_t)ND*DD);
    // pooling + transformer scratch overlays conv scratch
    off = region;
    float* hvec = (float*)alloc(NHOM);
    int* erow   = (int*)alloc(EHOM);
    int* ecol   = (int*)alloc(EHOM);
    float* esc  = (float*)alloc(EHOM);
    uint32_t* pmk = (uint32_t*)alloc(NHOM);
    float* pden = (float*)alloc(NHOM);      // pden,pscore contiguous zero region
    float* pscore = (float*)alloc(NHOM);
    int* seln   = (int*)alloc(BB*KPOOL);
    float* sels = (float*)alloc(BB*KPOOL);
    float* xp   = (float*)alloc((size_t)BB*KPOOL*DD);
    float* qb   = (float*)alloc((size_t)BB*KPOOL*DD);
    float* kb   = (float*)alloc((size_t)BB*KPOOL*DD);
    float* vb   = (float*)alloc((size_t)BB*KPOOL*DD);
    float* ao   = (float*)alloc((size_t)BB*KPOOL*DD);
    float* o2   = (float*)alloc((size_t)BB*KPOOL*DD);
    float* gatt = (float*)alloc((size_t)BB*KPOOL*DD);

    const int st_tab[2][4] = {{0,1,0,0},{0,0,1,0}};
    const int dt_tab[2][4] = {{0,0,1,0},{0,1,0,0}};

    // zero u/v accumulators
    fill_u32<<<(2*BB*512+255)/256,256,0,stream>>>((uint32_t*)ubuf, 0u, 2*BB*512);
    // fold arel/mrel into Wk/Wv (one launch)
    combine_all<<<dim3(256,32),256,0,stream>>>(hgt_Wk, hgt_Wv, hgt_arel, hgt_mrel, wtk, wtv);

    for(int bi=0;bi<2;bi++){
        int ib = bi*6;
        const float* x_inst = (const float*)d_in[ib+0];
        const float* x_data = (const float*)d_in[ib+1];
        const int* ecp = (const int*)d_in[ib+2];
        const int* eip = (const int*)d_in[ib+3];
        const int* eop = (const int*)d_in[ib+4];
        const int* ekp = (const int*)d_in[ib+5];
        const int* rows_f[4] = {ecp, eip, eop, ekp};
        const int* cols_f[4] = {ecp+EC, eip+EI, eop+EO, ekp+EK};
        const int* rows_r[4] = {ecp+EC, eip+EI, eop+EO, ekp+EK};
        const int* cols_r[4] = {ecp, eip, eop, ekp};

        const float* cur_i = x_inst;
        const float* cur_d = x_data;
        for(int l=0;l<LL;l++){
            float* nxt_i = (l==0) ? xa_i : xb_i;
            float* nxt_d = (l==0) ? xa_d : xb_d;
            for(int dir=0;dir<2;dir++){
                int wb = l*2 + dir;
                const int** rows = dir ? rows_r : rows_f;
                const int** cols = dir ? cols_r : cols_f;

                // --- batched GEMM: Q(2) + VM(4) + KA(4) ---
                GArgs g1; int nb1 = 0, ndx = 0;
                auto addg = [&](const float* A, const float* Bm, float* Cm, int M, int gl){
                    g1.d[ndx].A = A; g1.d[ndx].B = Bm; g1.d[ndx].C = Cm;
                    g1.d[ndx].mblks = M/GBM; g1.d[ndx].gelu = gl;
                    nb1 += M/GBM; ndx++;
                };
                addg(cur_i, hgt_Wq + (size_t)(wb*2+0)*65536, q_i, NI, 0);
                addg(cur_d, hgt_Wq + (size_t)(wb*2+1)*65536, q_d, ND, 0);
                for(int r=0;r<4;r++){
                    int st = st_tab[dir][r];
                    const float* xs = st ? cur_d : cur_i;
                    int ns = st ? ND : NI;
                    addg(xs, wtv + (size_t)(wb*4+r)*65536, vmb + (size_t)r*NI*DD, ns, 0);
                }
                for(int r=0;r<4;r++){
                    int st = st_tab[dir][r];
                    const float* xs = st ? cur_d : cur_i;
                    int ns = st ? ND : NI;
                    addg(xs, wtk + (size_t)(wb*4+r)*65536, ka4 + (size_t)r*NI*DD, ns, 0);
                }
                g1.nd = ndx;
                gemm_batch<<<dim3(nb1,2),256,0,stream>>>(g1);

                // --- init segment-softmax state (2 merged fills) ---
                fill_u32<<<((NI+ND)*HH+255)/256,256,0,stream>>>(mk_i, ENC_NEG_INF, (NI+ND)*HH);
                int zn = (NI+ND)*HH + (NI+ND)*DD;
                fill_u32<<<(zn+255)/256,256,0,stream>>>((uint32_t*)den_i, 0u, zn);

                // --- edge passes (merged over relations) ---
                EArgs ea;
                for(int r=0;r<4;r++){
                    ea.row[r] = rows[r]; ea.col[r] = cols[r];
                    ea.KA[r] = ka4 + (size_t)r*NI*DD;
                    ea.VM[r] = vmb + (size_t)r*NI*DD;
                    ea.dt[r] = dt_tab[dir][r];
                }
                ea.Q[0]=q_i; ea.Q[1]=q_d;
                ea.mk[0]=mk_i; ea.mk[1]=mk_d;
                ea.den[0]=den_i; ea.den[1]=den_d;
                ea.agg[0]=agg_i; ea.agg[1]=agg_d;
                ea.prel = hgt_prel + (size_t)wb*4*HH;
                ea.sc = scb;
                int eg = (EHGT*HH+255)/256;
                hgt_pass1<<<eg,256,0,stream>>>(ea);
                hgt_pass2<<<eg,256,0,stream>>>(ea);
                hgt_pass3<<<eg,256,0,stream>>>(ea);

                // --- Wo GEMMs (gelu on A), outputs into q_i/q_d (free now) ---
                GArgs g2; g2.nd = 2;
                g2.d[0].A=agg_i; g2.d[0].B=hgt_Wo + (size_t)(wb*2+0)*65536; g2.d[0].C=q_i; g2.d[0].mblks=NI/GBM; g2.d[0].gelu=1;
                g2.d[1].A=agg_d; g2.d[1].B=hgt_Wo + (size_t)(wb*2+1)*65536; g2.d[1].C=q_d; g2.d[1].mblks=ND/GBM; g2.d[1].gelu=1;
                gemm_batch<<<dim3(NI/GBM + ND/GBM,2),256,0,stream>>>(g2);

                hgt_epilogue<<<(NI*DD+255)/256,256,0,stream>>>(q_i, cur_i, hgt_skip + wb*2, 0, NI, xacc_i, nxt_i, dir);
                hgt_epilogue<<<(ND*DD+255)/256,256,0,stream>>>(q_d, cur_d, hgt_skip + wb*2, 1, ND, xacc_d, nxt_d, dir);
            }
            cur_i = nxt_i;
            cur_d = nxt_d;
        }

        // -------- SAGPooling --------
        pool_h<<<NI/4,256,0,stream>>>(cur_i, pool_W, hvec, NI);
        pool_h<<<ND/4,256,0,stream>>>(cur_d, pool_W, hvec+NI, ND);
        build_hom_edges<<<(EHOM+255)/256,256,0,stream>>>(ecp, eip, eop, ekp, erow, ecol);
        fill_u32<<<(NHOM+255)/256,256,0,stream>>>(pmk, ENC_NEG_INF, NHOM);
        fill_u32<<<(2*NHOM+255)/256,256,0,stream>>>((uint32_t*)pden, 0u, 2*NHOM);
        pool_pass1<<<(EHOM+255)/256,256,0,stream>>>(erow, ecol, hvec, pool_att, esc, pmk);
        pool_pass2<<<(EHOM+255)/256,256,0,stream>>>(ecol, esc, pmk, pden);
        pool_pass3<<<(EHOM+255)/256,256,0,stream>>>(erow, ecol, esc, pden, hvec, pscore);
        topk_kernel<<<BB,512,0,stream>>>(pscore, pool_bias, seln, sels);
        gather_xp<<<BB*KPOOL,256,0,stream>>>(seln, sels, cur_i, cur_d, xp);

        // -------- transformer --------
        int MR = BB*KPOOL;  // 6144
        GArgs g3; g3.nd = 3;
        g3.d[0].A=xp; g3.d[0].B=t_wq; g3.d[0].C=qb; g3.d[0].mblks=MR/GBM; g3.d[0].gelu=0;
        g3.d[1].A=xp; g3.d[1].B=t_wk; g3.d[1].C=kb; g3.d[1].mblks=MR/GBM; g3.d[1].gelu=0;
        g3.d[2].A=xp; g3.d[2].B=t_wv; g3.d[2].C=vb; g3.d[2].mblks=MR/GBM; g3.d[2].gelu=0;
        gemm_batch<<<dim3(3*(MR/GBM),2),256,0,stream>>>(g3);
        attn_kernel<<<BB*HH*KPOOL/4,256,0,stream>>>(qb, kb, vb, ao);
        GArgs g4; g4.nd = 1;
        g4.d[0].A=ao; g4.d[0].B=t_wo; g4.d[0].C=o2; g4.d[0].mblks=MR/GBM; g4.d[0].gelu=0;
        gemm_batch<<<dim3(MR/GBM,2),256,0,stream>>>(g4);
        ln_kernel<<<MR,256,0,stream>>>(xp, o2, ln_g, ln_b, gatt);
        feat_reduce2<<<dim3(BB,12),256,0,stream>>>(xp, gatt, bi ? vbuf : ubuf);
    }

    cosine_kernel<<<BB,64,0,stream>>>(ubuf, vbuf, out);
}

// Round 3
// 3390.009 us; speedup vs baseline: 6.5454x; 5.5104x over previous
//
#include <hip/hip_runtime.h>
#include <math.h>
#include <stdint.h>

#define LL 2
#define HH 4
#define DHH 64
#define DD 256
#define BB 8
#define NI 8192
#define ND 4096
#define NROW 12288
#define NHOM 12288
#define KPOOL 768
#define EC 65536
#define EI 32768
#define EO 32768
#define EK 8192
#define EHGT (EC+EI+EO+EK)
#define EHOM (EC+EI+EO+EK+NHOM)
#define ENC_NEG_INF 0x007FFFFFu

#define GBM 128
#define GBN 128
#define GBK 16

__device__ inline float gelu_f(float x){ return 0.5f*x*(1.f+erff(x*0.70710678118654752f)); }
__device__ inline uint32_t fenc(float x){ uint32_t u=__float_as_uint(x); return (u&0x80000000u)? ~u : (u|0x80000000u); }
__device__ inline float fdec(uint32_t k){ return (k&0x80000000u)? __uint_as_float(k&0x7fffffffu) : __uint_as_float(~k); }

// ---------------- generic fill ----------------
__global__ void fill_u32(uint32_t* p, uint32_t v, int n){
    int i = blockIdx.x*256 + threadIdx.x;
    if(i<n) p[i]=v;
}

// ---------------- batched GEMM: C[M,256] = (gelu?)A[M,256] @ B[256,256] ----------------
struct GDesc { const float* A; const float* B; float* C; int mblks; int gelu; };
struct GArgs { GDesc d[12]; int nd; };

__global__ __launch_bounds__(256) void gemm_batch(GArgs ga){
    __shared__ float As[GBK][GBM+4];
    __shared__ float Bs[GBK][GBN+4];
    int mb = blockIdx.x;
    int di = 0;
    while(di < ga.nd-1 && mb >= ga.d[di].mblks){ mb -= ga.d[di].mblks; di++; }
    const float* __restrict__ A = ga.d[di].A;
    const float* __restrict__ B = ga.d[di].B;
    float* __restrict__ C = ga.d[di].C;
    const int gelu = ga.d[di].gelu;
    const int m0 = mb*GBM, n0 = blockIdx.y*GBN;
    const int tid = threadIdx.x;
    const int tx = tid & 15, ty = tid >> 4;
    const int arow = tid >> 1, acol = (tid & 1)*8;
    const int brow = tid >> 4, bcol = (tid & 15)*8;
    const float* Aptr = A + (size_t)(m0+arow)*DD + acol;
    const float* Bptr = B + (size_t)brow*DD + n0 + bcol;
    float acc[8][8] = {};
    for(int k0=0;k0<DD;k0+=GBK){
        float4 a0 = *(const float4*)(Aptr + k0);
        float4 a1 = *(const float4*)(Aptr + k0 + 4);
        float4 b0 = *(const float4*)(Bptr + (size_t)k0*DD);
        float4 b1 = *(const float4*)(Bptr + (size_t)k0*DD + 4);
        if(gelu){
            a0.x=gelu_f(a0.x); a0.y=gelu_f(a0.y); a0.z=gelu_f(a0.z); a0.w=gelu_f(a0.w);
            a1.x=gelu_f(a1.x); a1.y=gelu_f(a1.y); a1.z=gelu_f(a1.z); a1.w=gelu_f(a1.w);
        }
        __syncthreads();
        As[acol+0][arow]=a0.x; As[acol+1][arow]=a0.y; As[acol+2][arow]=a0.z; As[acol+3][arow]=a0.w;
        As[acol+4][arow]=a1.x; As[acol+5][arow]=a1.y; As[acol+6][arow]=a1.z; As[acol+7][arow]=a1.w;
        *(float4*)&Bs[brow][bcol]   = b0;
        *(float4*)&Bs[brow][bcol+4] = b1;
        __syncthreads();
        #pragma unroll
        for(int kk=0;kk<GBK;kk++){
            float av[8], bv[8];
            *(float4*)&av[0] = *(const float4*)&As[kk][ty*8];
            *(float4*)&av[4] = *(const float4*)&As[kk][ty*8+4];
            *(float4*)&bv[0] = *(const float4*)&Bs[kk][tx*8];
            *(float4*)&bv[4] = *(const float4*)&Bs[kk][tx*8+4];
            #pragma unroll
            for(int i=0;i<8;i++)
                #pragma unroll
                for(int j=0;j<8;j++) acc[i][j] = fmaf(av[i], bv[j], acc[i][j]);
        }
    }
    float* Cp = C + (size_t)(m0+ty*8)*DD + n0 + tx*8;
    #pragma unroll
    for(int i=0;i<8;i++){
        float4 c0 = {acc[i][0],acc[i][1],acc[i][2],acc[i][3]};
        float4 c1 = {acc[i][4],acc[i][5],acc[i][6],acc[i][7]};
        *(float4*)(Cp + (size_t)i*DD)     = c0;
        *(float4*)(Cp + (size_t)i*DD + 4) = c1;
    }
}

// ---------- combine (all 32 (idx,kv) pairs in one launch) ----------
__global__ void combine_all(const float* __restrict__ Wk, const float* __restrict__ Wv,
                            const float* __restrict__ Ra, const float* __restrict__ Rm,
                            float* __restrict__ wtk, float* __restrict__ wtv){
    const int st_tab[2][4] = {{0,1,0,0},{0,0,1,0}};
    int combo = blockIdx.y;             // 0..31
    int idx = combo >> 1, kv = combo & 1;
    int r = idx & 3, wb = idx >> 2, dir = wb & 1;
    int st = st_tab[dir][r];
    const float* W = (kv ? Wv : Wk) + (size_t)(wb*2 + st)*65536;
    const float* R = (kv ? Rm : Ra) + (size_t)idx*16384;
    float* o = (kv ? wtv : wtk) + (size_t)idx*65536;
    int d = blockIdx.x, c = threadIdx.x;
    int h = c >> 6, f = c & 63;
    const float* Wrow = W + d*DD + h*64;
    const float* Rh = R + h*4096 + f;
    float s = 0.f;
    #pragma unroll 8
    for(int k=0;k<64;k++) s += Wrow[k]*Rh[k*64];
    o[d*DD + c] = s;
}

// ---------------- CSR build ----------------
__device__ inline void edge_decode(int e, int& r, int& el){
    if(e < EC){ r=0; el=e; }
    else if(e < EC+EI){ r=1; el=e-EC; }
    else if(e < EC+EI+EO){ r=2; el=e-(EC+EI); }
    else { r=3; el=e-(EC+EI+EO); }
}

struct CBArgs {
    const int* row[4]; const int* col[4];
    int dt[4];
    uint32_t* cnt; uint32_t* rowptr; uint32_t* einfo; uint32_t* slot;
};

__global__ void csr_hist(CBArgs a){
    int ge = blockIdx.x*256 + threadIdx.x;
    if(ge >= EHGT) return;
    int r, el; edge_decode(ge, r, el);
    int c = a.col[r][el];
    int dst = a.dt[r] ? (NI + c) : c;
    atomicAdd(&a.cnt[dst], 1u);
}

__global__ __launch_bounds__(1024) void scan_rowptr(uint32_t* cnt, uint32_t* rowptr){
    __shared__ uint32_t part[1024];
    int t = threadIdx.x;
    int base = t*12;
    uint32_t lpre[12];
    uint32_t sum = 0;
    #pragma unroll
    for(int i=0;i<12;i++){
        uint32_t c = cnt[base+i];
        lpre[i] = sum; sum += c;
        cnt[base+i] = 0;           // re-zero for scatter phase
    }
    part[t] = sum;
    __syncthreads();
    for(int offs=1; offs<1024; offs<<=1){
        uint32_t v = (t>=offs) ? part[t-offs] : 0u;
        __syncthreads();
        part[t] += v;
        __syncthreads();
    }
    uint32_t pre = (t==0) ? 0u : part[t-1];
    #pragma unroll
    for(int i=0;i<12;i++) rowptr[base+i] = pre + lpre[i];
    if(t==1023) rowptr[NROW] = part[1023];
}

__global__ void csr_scatter(CBArgs a){
    int ge = blockIdx.x*256 + threadIdx.x;
    if(ge >= EHGT) return;
    int r, el; edge_decode(ge, r, el);
    int c = a.col[r][el];
    int dst = a.dt[r] ? (NI + c) : c;
    int src = a.row[r][el];
    uint32_t p = a.rowptr[dst] + atomicAdd(&a.cnt[dst], 1u);
    a.einfo[p] = (uint32_t)src | ((uint32_t)r << 16);
    a.slot[ge] = p;
}

// ---------------- HGT edge phase ----------------
struct P1Args {
    const int* row[4]; const int* col[4];
    const float* Q[2];
    const float* ka;          // + r*NI*DD
    const float* prel;        // prel[r*HH + h]
    const uint32_t* slot;
    float* sc;
    int dt[4];
};

__global__ void hgt_pass1(P1Args a){
    int i = blockIdx.x*256 + threadIdx.x;
    if(i >= EHGT*HH) return;
    int ge = i >> 2, h = i & 3;
    int r, el; edge_decode(ge, r, el);
    int dt = a.dt[r];
    int rn = a.row[r][el], cn = a.col[r][el];
    const float* q  = a.Q[dt] + (size_t)cn*DD + h*64;
    const float* ka = a.ka + (size_t)r*NI*DD + (size_t)rn*DD + h*64;
    float s = 0.f;
    #pragma unroll 8
    for(int d=0;d<64;d++) s += q[d]*ka[d];
    s *= a.prel[r*HH + h]*0.125f;
    a.sc[(size_t)a.slot[ge]*HH + h] = s;
}

// one wave per (dst,h): segment softmax + weighted gather, no atomics
__global__ __launch_bounds__(256) void hgt_rowpass(const uint32_t* __restrict__ rowptr,
                                                   const uint32_t* __restrict__ einfo,
                                                   const float* __restrict__ sc,
                                                   const float* __restrict__ vmb,
                                                   float* __restrict__ agg_i,
                                                   float* __restrict__ agg_d){
    int w = blockIdx.x*4 + (threadIdx.x >> 6);
    int lane = threadIdx.x & 63;
    int rowi = w >> 2, h = w & 3;
    uint32_t p0 = rowptr[rowi], p1 = rowptr[rowi+1];
    float* ag = (rowi < NI) ? (agg_i + (size_t)rowi*DD + h*64)
                            : (agg_d + (size_t)(rowi-NI)*DD + h*64);
    if(p0 == p1){ ag[lane] = 0.f; return; }
    float m = -INFINITY;
    for(uint32_t p = p0+lane; p < p1; p += 64) m = fmaxf(m, sc[(size_t)p*HH + h]);
    #pragma unroll
    for(int s=32;s;s>>=1) m = fmaxf(m, __shfl_xor(m, s));
    float den = 0.f;
    for(uint32_t p = p0+lane; p < p1; p += 64) den += expf(sc[(size_t)p*HH + h] - m);
    #pragma unroll
    for(int s=32;s;s>>=1) den += __shfl_xor(den, s);
    float inv = 1.f/(den + 1e-16f);
    float o = 0.f;
    for(uint32_t p = p0; p < p1; p++){
        uint32_t ei = einfo[p];
        int src = ei & 0xffff, r = ei >> 16;
        float alpha = expf(sc[(size_t)p*HH + h] - m) * inv;
        o += alpha * vmb[((size_t)r*NI + src)*DD + h*64 + lane];
    }
    ag[lane] = o;
}

// epilogue: val = sig(skip[t])*o + (1-sig)*x ; mode0: xacc=0.5*val ; mode1: xnext=relu(xacc+0.5*val)
__global__ void hgt_epilogue(const float* __restrict__ o, const float* __restrict__ x,
                             const float* __restrict__ skip, int t, int n,
                             float* __restrict__ xacc, float* __restrict__ xnext, int mode){
    int i = blockIdx.x*256 + threadIdx.x;
    if(i >= n*DD) return;
    float g = 1.f/(1.f + expf(-skip[t]));
    float val = g*o[i] + (1.f-g)*x[i];
    if(mode==0){
        xacc[i] = 0.5f*val;
    } else {
        float v2 = xacc[i] + 0.5f*val;
        xnext[i] = v2 > 0.f ? v2 : 0.f;
    }
}

// ---------------- pooling ----------------
__global__ void pool_h(const float* __restrict__ x, const float* __restrict__ w,
                       float* __restrict__ h, int n){
    int node = blockIdx.x*4 + (threadIdx.x>>6);
    int lane = threadIdx.x & 63;
    if(node >= n) return;
    const float* xr = x + (size_t)node*DD;
    float s = 0.f;
    for(int j=lane;j<DD;j+=64) s += xr[j]*w[j];
    for(int m=32;m;m>>=1) s += __shfl_xor(s, m);
    if(lane==0) h[node] = s;
}

__global__ void build_hom_edges(const int* __restrict__ ec, const int* __restrict__ ei,
                                const int* __restrict__ eo, const int* __restrict__ ek,
                                int* __restrict__ erow, int* __restrict__ ecol){
    int i = blockIdx.x*256 + threadIdx.x;
    if(i >= EHOM) return;
    int r, c;
    if(i < EC){ r = ec[i]; c = ec[i+EC]; }
    else if(i < EC+EI){ int j=i-EC; r = ei[j]+NI; c = ei[j+EI]; }
    else if(i < EC+EI+EO){ int j=i-(EC+EI); r = eo[j]; c = eo[j+EO]+NI; }
    else if(i < EHGT){ int j=i-(EC+EI+EO); r = ek[j]; c = ek[j+EK]; }
    else { int j=i-EHGT; r = j; c = j; }
    erow[i] = r; ecol[i] = c;
}

__global__ void pool_pass1(const int* __restrict__ row, const int* __restrict__ col,
                           const float* __restrict__ h, const float* __restrict__ att,
                           float* __restrict__ esc, uint32_t* __restrict__ mx){
    int i = blockIdx.x*256 + threadIdx.x;
    if(i>=EHOM) return;
    float e = att[0]*h[row[i]] + att[1]*h[col[i]];
    e = e >= 0.f ? e : 0.2f*e;
    esc[i] = e;
    atomicMax(&mx[col[i]], fenc(e));
}
__global__ void pool_pass2(const int* __restrict__ col, float* __restrict__ esc,
                           const uint32_t* __restrict__ mx, float* __restrict__ den){
    int i = blockIdx.x*256 + threadIdx.x;
    if(i>=EHOM) return;
    float a = expf(esc[i] - fdec(mx[col[i]]));
    esc[i] = a;
    atomicAdd(&den[col[i]], a);
}
__global__ void pool_pass3(const int* __restrict__ row, const int* __restrict__ col,
                           const float* __restrict__ esc, const float* __restrict__ den,
                           const float* __restrict__ h, float* __restrict__ score){
    int i = blockIdx.x*256 + threadIdx.x;
    if(i>=EHOM) return;
    atomicAdd(&score[col[i]], esc[i]/(den[col[i]]+1e-16f) * h[row[i]]);
}

// top-768 of 1536 per graph via bitonic sort (pad to 2048)
__global__ __launch_bounds__(512) void topk_kernel(const float* __restrict__ score,
                                                   const float* __restrict__ bias,
                                                   int* __restrict__ sel_node,
                                                   float* __restrict__ sel_scale){
    __shared__ float skey[2048];
    __shared__ int   sval[2048];
    int b = blockIdx.x;
    float bv = bias[0];
    for(int p=threadIdx.x;p<2048;p+=512){
        if(p<1536){
            int node = (p<1024) ? (b*1024 + p) : (NI + b*512 + (p-1024));
            skey[p] = score[node] + bv;
            sval[p] = node;
        } else {
            skey[p] = -INFINITY;
            sval[p] = -1;
        }
    }
    for(int k=2;k<=2048;k<<=1){
        for(int j=k>>1;j>0;j>>=1){
            __syncthreads();
            for(int i=threadIdx.x;i<2048;i+=512){
                int ixj = i^j;
                if(ixj > i){
                    bool up = ((i & k) == 0);
                    float ki = skey[i], kj = skey[ixj];
                    if((ki < kj) == up){
                        skey[i]=kj; skey[ixj]=ki;
                        int t=sval[i]; sval[i]=sval[ixj]; sval[ixj]=t;
                    }
                }
            }
        }
    }
    __syncthreads();
    for(int j=threadIdx.x;j<KPOOL;j+=512){
        sel_node[b*KPOOL + j] = sval[j];
        sel_scale[b*KPOOL + j] = tanhf(skey[j]);
    }
}

__global__ void gather_xp(const int* __restrict__ sel, const float* __restrict__ scale,
                          const float* __restrict__ xi, const float* __restrict__ xd,
                          float* __restrict__ xp){
    int i = blockIdx.x*256 + threadIdx.x;
    int rowp = i >> 8, c = i & 255;
    int node = sel[rowp];
    float s = scale[rowp];
    float v = (node < NI) ? xi[(size_t)node*DD + c] : xd[(size_t)(node-NI)*DD + c];
    xp[i] = v*s;
}

// ---------------- flash attention: block per (b,h,64-row q tile) ----------------
__global__ __launch_bounds__(256) void attn_flash(const float* __restrict__ Qb,
                                                  const float* __restrict__ Kb,
                                                  const float* __restrict__ Vb,
                                                  float* __restrict__ Ob){
    __shared__ float Qs[64][65];
    __shared__ float Ks[64][65];
    __shared__ float Vs[64][65];
    int bh = blockIdx.y;
    int b = bh >> 2, h = bh & 3;
    int q0 = blockIdx.x * 64;
    int tid = threadIdx.x;
    int tx = tid & 15, ty = tid >> 4;
    #pragma unroll
    for(int k=0;k<4;k++){
        int idx = tid + k*256;
        int r = idx >> 4, c = (idx & 15)*4;
        float4 v = *(const float4*)(Qb + ((size_t)(b*KPOOL + q0 + r))*DD + h*64 + c);
        Qs[r][c]=v.x; Qs[r][c+1]=v.y; Qs[r][c+2]=v.z; Qs[r][c+3]=v.w;
    }
    float m[4], l[4], O[4][4];
    #pragma unroll
    for(int i=0;i<4;i++){ m[i]=-INFINITY; l[i]=0.f;
        #pragma unroll
        for(int j=0;j<4;j++) O[i][j]=0.f; }
    for(int k0=0;k0<KPOOL;k0+=64){
        __syncthreads();
        #pragma unroll
        for(int k=0;k<4;k++){
            int idx = tid + k*256;
            int r = idx >> 4, c = (idx & 15)*4;
            float4 kv = *(const float4*)(Kb + ((size_t)(b*KPOOL + k0 + r))*DD + h*64 + c);
            float4 vv = *(const float4*)(Vb + ((size_t)(b*KPOOL + k0 + r))*DD + h*64 + c);
            Ks[r][c]=kv.x; Ks[r][c+1]=kv.y; Ks[r][c+2]=kv.z; Ks[r][c+3]=kv.w;
            Vs[r][c]=vv.x; Vs[r][c+1]=vv.y; Vs[r][c+2]=vv.z; Vs[r][c+3]=vv.w;
        }
        __syncthreads();
        float s[4][4] = {};
        for(int d=0;d<64;d++){
            float qv[4], kv[4];
            #pragma unroll
            for(int i=0;i<4;i++) qv[i]=Qs[ty*4+i][d];
            #pragma unroll
            for(int j=0;j<4;j++) kv[j]=Ks[tx*4+j][d];
            #pragma unroll
            for(int i=0;i<4;i++)
                #pragma unroll
                for(int j=0;j<4;j++) s[i][j] = fmaf(qv[i], kv[j], s[i][j]);
        }
        float p[4][4];
        #pragma unroll
        for(int i=0;i<4;i++){
            #pragma unroll
            for(int j=0;j<4;j++) s[i][j] *= 0.125f;
            float tm = fmaxf(fmaxf(s[i][0],s[i][1]), fmaxf(s[i][2],s[i][3]));
            #pragma unroll
            for(int msk=8;msk;msk>>=1) tm = fmaxf(tm, __shfl_xor(tm, msk));
            float nm = fmaxf(m[i], tm);
            float esc = expf(m[i]-nm);
            float ps = 0.f;
            #pragma unroll
            for(int j=0;j<4;j++){ p[i][j] = expf(s[i][j]-nm); ps += p[i][j]; }
            #pragma unroll
            for(int msk=8;msk;msk>>=1) ps += __shfl_xor(ps, msk);
            l[i] = l[i]*esc + ps;
            m[i] = nm;
            #pragma unroll
            for(int j=0;j<4;j++) O[i][j] *= esc;
        }
        // O += P @ V  (P exchanged via in-wave shuffles; wave = 4 ty-groups of 16)
        #pragma unroll
        for(int kb=0;kb<16;kb++){
            int srcl = ((ty&3)<<4) + kb;
            #pragma unroll
            for(int kj=0;kj<4;kj++){
                int kk = kb*4 + kj;
                float vv[4];
                #pragma unroll
                for(int j=0;j<4;j++) vv[j] = Vs[kk][tx*4+j];
                #pragma unroll
                for(int i=0;i<4;i++){
                    float pv = __shfl(p[i][kj], srcl, 64);
                    #pragma unroll
                    for(int j=0;j<4;j++) O[i][j] = fmaf(pv, vv[j], O[i][j]);
                }
            }
        }
    }
    #pragma unroll
    for(int i=0;i<4;i++){
        float inv = 1.f/l[i];
        #pragma unroll
        for(int j=0;j<4;j++)
            Ob[((size_t)(b*KPOOL + q0 + ty*4 + i))*DD + h*64 + tx*4 + j] = O[i][j]*inv;
    }
}

// layernorm row kernel: y = xp + o2 ; gatt = g*(y-mu)/sqrt(var+eps)+b
__global__ __launch_bounds__(256) void ln_kernel(const float* __restrict__ xp, const float* __restrict__ o2,
                                                 const float* __restrict__ lg, const float* __restrict__ lb,
                                                 float* __restrict__ gatt){
    __shared__ float red[256];
    int r = blockIdx.x, c = threadIdx.x;
    float y = xp[(size_t)r*DD + c] + o2[(size_t)r*DD + c];
    red[c] = y; __syncthreads();
    for(int s=128;s;s>>=1){ if(c<s) red[c] += red[c+s]; __syncthreads(); }
    float mu = red[0]*(1.f/DD);
    __syncthreads();
    float d = y - mu;
    red[c] = d*d; __syncthreads();
    for(int s=128;s;s>>=1){ if(c<s) red[c] += red[c+s]; __syncthreads(); }
    float var = red[0]*(1.f/DD);
    gatt[(size_t)r*DD + c] = lg[c]*d/sqrtf(var+1e-5f) + lb[c];
}

__global__ void feat_reduce2(const float* __restrict__ xp, const float* __restrict__ gatt,
                             float* __restrict__ out){
    int b = blockIdx.x, c = threadIdx.x;
    int j0 = blockIdx.y*64;
    float s1=0.f, s2=0.f;
    for(int j=j0;j<j0+64;j++){
        size_t base = ((size_t)(b*KPOOL + j))*DD + c;
        s1 += xp[base];
        s2 += gatt[base];
    }
    atomicAdd(&out[b*512 + c], s1);
    atomicAdd(&out[b*512 + 256 + c], s2);
}

__global__ void cosine_kernel(const float* __restrict__ u, const float* __restrict__ v,
                              float* __restrict__ out){
    int b = blockIdx.x, t = threadIdx.x;
    float du=0.f, nu=0.f, nv=0.f;
    for(int j=t;j<512;j+=64){
        float a = u[b*512+j], bb = v[b*512+j];
        du += a*bb; nu += a*a; nv += bb*bb;
    }
    for(int m=32;m;m>>=1){
        du += __shfl_xor(du,m); nu += __shfl_xor(nu,m); nv += __shfl_xor(nv,m);
    }
    if(t==0) out[b] = du / (fmaxf(sqrtf(nu),1e-8f)*fmaxf(sqrtf(nv),1e-8f));
}

// =======================================================================
extern "C" void kernel_launch(void* const* d_in, const int* in_sizes, int n_in,
                              void* d_out, int out_size, void* d_ws, size_t ws_size,
                              hipStream_t stream){
    (void)in_sizes; (void)n_in; (void)out_size; (void)ws_size;
    const float* hgt_Wk   = (const float*)d_in[12];
    const float* hgt_Wq   = (const float*)d_in[13];
    const float* hgt_Wv   = (const float*)d_in[14];
    const float* hgt_Wo   = (const float*)d_in[15];
    const float* hgt_arel = (const float*)d_in[16];
    const float* hgt_mrel = (const float*)d_in[17];
    const float* hgt_prel = (const float*)d_in[18];
    const float* hgt_skip = (const float*)d_in[19];
    const float* pool_W   = (const float*)d_in[20];
    const float* pool_att = (const float*)d_in[21];
    const float* pool_bias= (const float*)d_in[22];
    const float* t_wq     = (const float*)d_in[23];
    const float* t_wk     = (const float*)d_in[24];
    const float* t_wv     = (const float*)d_in[25];
    const float* t_wo     = (const float*)d_in[26];
    const float* ln_g     = (const float*)d_in[27];
    const float* ln_b     = (const float*)d_in[28];
    float* out = (float*)d_out;

    char* base = (char*)d_ws;
    size_t off = 0;
    auto alloc = [&](size_t nElems)->void*{
        void* p = (void*)(base + off);
        off += ((nElems*4 + 255) & ~(size_t)255);
        return p;
    };
    // persistent
    float* wtk  = (float*)alloc(16*65536);
    float* wtv  = (float*)alloc(16*65536);
    float* ubuf = (float*)alloc(BB*512);
    float* vbuf = (float*)alloc(BB*512);
    float* xa_i = (float*)alloc((size_t)NI*DD);
    float* xa_d = (float*)alloc((size_t)ND*DD);
    float* xb_i = (float*)alloc((size_t)NI*DD);
    float* xb_d = (float*)alloc((size_t)ND*DD);
    size_t region = off;
    // conv scratch (CSR first; overlaid by pooling after convs)
    uint32_t* ccnt    = (uint32_t*)alloc(NROW);
    uint32_t* rowp2[2]; uint32_t* einf2[2]; uint32_t* slot2[2];
    for(int d=0; d<2; d++){
        rowp2[d] = (uint32_t*)alloc(NROW+1);
        einf2[d] = (uint32_t*)alloc(EHGT);
        slot2[d] = (uint32_t*)alloc(EHGT);
    }
    float* q_i  = (float*)alloc((size_t)NI*DD);   // also reused as ob_i
    float* q_d  = (float*)alloc((size_t)ND*DD);   // also reused as ob_d
    float* ka4  = (float*)alloc((size_t)4*NI*DD);
    float* vmb  = (float*)alloc((size_t)4*NI*DD);
    float* scb  = (float*)alloc((size_t)EHGT*HH);
    float* agg_i = (float*)alloc((size_t)NI*DD);
    float* agg_d = (float*)alloc((size_t)ND*DD);
    float* xacc_i= (float*)alloc((size_t)NI*DD);
    float* xacc_d= (float*)alloc((size_t)ND*DD);
    // pooling + transformer scratch overlays conv scratch
    off = region;
    float* hvec = (float*)alloc(NHOM);
    int* erow   = (int*)alloc(EHOM);
    int* ecol   = (int*)alloc(EHOM);
    float* esc  = (float*)alloc(EHOM);
    uint32_t* pmk = (uint32_t*)alloc(NHOM);
    float* pden = (float*)alloc(NHOM);
    float* pscore = (float*)alloc(NHOM);
    int* seln   = (int*)alloc(BB*KPOOL);
    float* sels = (float*)alloc(BB*KPOOL);
    float* xp   = (float*)alloc((size_t)BB*KPOOL*DD);
    float* qb   = (float*)alloc((size_t)BB*KPOOL*DD);
    float* kb   = (float*)alloc((size_t)BB*KPOOL*DD);
    float* vb   = (float*)alloc((size_t)BB*KPOOL*DD);
    float* ao   = (float*)alloc((size_t)BB*KPOOL*DD);
    float* o2   = (float*)alloc((size_t)BB*KPOOL*DD);
    float* gatt = (float*)alloc((size_t)BB*KPOOL*DD);

    const int st_tab[2][4] = {{0,1,0,0},{0,0,1,0}};
    const int dt_tab[2][4] = {{0,0,1,0},{0,1,0,0}};

    // zero u/v accumulators
    fill_u32<<<(2*BB*512+255)/256,256,0,stream>>>((uint32_t*)ubuf, 0u, 2*BB*512);
    // fold arel/mrel into Wk/Wv (one launch)
    combine_all<<<dim3(256,32),256,0,stream>>>(hgt_Wk, hgt_Wv, hgt_arel, hgt_mrel, wtk, wtv);

    for(int bi=0;bi<2;bi++){
        int ib = bi*6;
        const float* x_inst = (const float*)d_in[ib+0];
        const float* x_data = (const float*)d_in[ib+1];
        const int* ecp = (const int*)d_in[ib+2];
        const int* eip = (const int*)d_in[ib+3];
        const int* eop = (const int*)d_in[ib+4];
        const int* ekp = (const int*)d_in[ib+5];
        const int* rows_f[4] = {ecp, eip, eop, ekp};
        const int* cols_f[4] = {ecp+EC, eip+EI, eop+EO, ekp+EK};
        const int* rows_r[4] = {ecp+EC, eip+EI, eop+EO, ekp+EK};
        const int* cols_r[4] = {ecp, eip, eop, ekp};

        // ---- CSR build per direction (edges fixed across layers) ----
        for(int dir=0; dir<2; dir++){
            CBArgs cb;
            for(int r=0;r<4;r++){
                cb.row[r] = dir ? rows_r[r] : rows_f[r];
                cb.col[r] = dir ? cols_r[r] : cols_f[r];
                cb.dt[r] = dt_tab[dir][r];
            }
            cb.cnt = ccnt; cb.rowptr = rowp2[dir]; cb.einfo = einf2[dir]; cb.slot = slot2[dir];
            fill_u32<<<(NROW+255)/256,256,0,stream>>>(ccnt, 0u, NROW);
            csr_hist<<<(EHGT+255)/256,256,0,stream>>>(cb);
            scan_rowptr<<<1,1024,0,stream>>>(ccnt, rowp2[dir]);
            csr_scatter<<<(EHGT+255)/256,256,0,stream>>>(cb);
        }

        const float* cur_i = x_inst;
        const float* cur_d = x_data;
        for(int l=0;l<LL;l++){
            float* nxt_i = (l==0) ? xa_i : xb_i;
            float* nxt_d = (l==0) ? xa_d : xb_d;
            for(int dir=0;dir<2;dir++){
                int wb = l*2 + dir;
                const int** rows = dir ? rows_r : rows_f;
                const int** cols = dir ? cols_r : cols_f;

                // --- batched GEMM: Q(2) + VM(4) + KA(4) ---
                GArgs g1; int nb1 = 0, ndx = 0;
                auto addg = [&](const float* A, const float* Bm, float* Cm, int M, int gl){
                    g1.d[ndx].A = A; g1.d[ndx].B = Bm; g1.d[ndx].C = Cm;
                    g1.d[ndx].mblks = M/GBM; g1.d[ndx].gelu = gl;
                    nb1 += M/GBM; ndx++;
                };
                addg(cur_i, hgt_Wq + (size_t)(wb*2+0)*65536, q_i, NI, 0);
                addg(cur_d, hgt_Wq + (size_t)(wb*2+1)*65536, q_d, ND, 0);
                for(int r=0;r<4;r++){
                    int st = st_tab[dir][r];
                    const float* xs = st ? cur_d : cur_i;
                    int ns = st ? ND : NI;
                    addg(xs, wtv + (size_t)(wb*4+r)*65536, vmb + (size_t)r*NI*DD, ns, 0);
                }
                for(int r=0;r<4;r++){
                    int st = st_tab[dir][r];
                    const float* xs = st ? cur_d : cur_i;
                    int ns = st ? ND : NI;
                    addg(xs, wtk + (size_t)(wb*4+r)*65536, ka4 + (size_t)r*NI*DD, ns, 0);
                }
                g1.nd = ndx;
                gemm_batch<<<dim3(nb1,2),256,0,stream>>>(g1);

                // --- edge scores into CSR slots ---
                P1Args pa;
                for(int r=0;r<4;r++){
                    pa.row[r] = rows[r]; pa.col[r] = cols[r];
                    pa.dt[r] = dt_tab[dir][r];
                }
                pa.Q[0]=q_i; pa.Q[1]=q_d;
                pa.ka = ka4;
                pa.prel = hgt_prel + (size_t)wb*4*HH;
                pa.slot = slot2[dir];
                pa.sc = scb;
                hgt_pass1<<<(EHGT*HH+255)/256,256,0,stream>>>(pa);

                // --- per-(dst,h) softmax + gather ---
                hgt_rowpass<<<NROW,256,0,stream>>>(rowp2[dir], einf2[dir], scb, vmb, agg_i, agg_d);

                // --- Wo GEMMs (gelu on A), outputs into q_i/q_d (free now) ---
                GArgs g2; g2.nd = 2;
                g2.d[0].A=agg_i; g2.d[0].B=hgt_Wo + (size_t)(wb*2+0)*65536; g2.d[0].C=q_i; g2.d[0].mblks=NI/GBM; g2.d[0].gelu=1;
                g2.d[1].A=agg_d; g2.d[1].B=hgt_Wo + (size_t)(wb*2+1)*65536; g2.d[1].C=q_d; g2.d[1].mblks=ND/GBM; g2.d[1].gelu=1;
                gemm_batch<<<dim3(NI/GBM + ND/GBM,2),256,0,stream>>>(g2);

                hgt_epilogue<<<(NI*DD+255)/256,256,0,stream>>>(q_i, cur_i, hgt_skip + wb*2, 0, NI, xacc_i, nxt_i, dir);
                hgt_epilogue<<<(ND*DD+255)/256,256,0,stream>>>(q_d, cur_d, hgt_skip + wb*2, 1, ND, xacc_d, nxt_d, dir);
            }
            cur_i = nxt_i;
            cur_d = nxt_d;
        }

        // -------- SAGPooling --------
        pool_h<<<NI/4,256,0,stream>>>(cur_i, pool_W, hvec, NI);
        pool_h<<<ND/4,256,0,stream>>>(cur_d, pool_W, hvec+NI, ND);
        build_hom_edges<<<(EHOM+255)/256,256,0,stream>>>(ecp, eip, eop, ekp, erow, ecol);
        fill_u32<<<(NHOM+255)/256,256,0,stream>>>(pmk, ENC_NEG_INF, NHOM);
        fill_u32<<<(2*NHOM+255)/256,256,0,stream>>>((uint32_t*)pden, 0u, 2*NHOM);
        pool_pass1<<<(EHOM+255)/256,256,0,stream>>>(erow, ecol, hvec, pool_att, esc, pmk);
        pool_pass2<<<(EHOM+255)/256,256,0,stream>>>(ecol, esc, pmk, pden);
        pool_pass3<<<(EHOM+255)/256,256,0,stream>>>(erow, ecol, esc, pden, hvec, pscore);
        topk_kernel<<<BB,512,0,stream>>>(pscore, pool_bias, seln, sels);
        gather_xp<<<BB*KPOOL,256,0,stream>>>(seln, sels, cur_i, cur_d, xp);

        // -------- transformer --------
        int MR = BB*KPOOL;  // 6144
        GArgs g3; g3.nd = 3;
        g3.d[0].A=xp; g3.d[0].B=t_wq; g3.d[0].C=qb; g3.d[0].mblks=MR/GBM; g3.d[0].gelu=0;
        g3.d[1].A=xp; g3.d[1].B=t_wk; g3.d[1].C=kb; g3.d[1].mblks=MR/GBM; g3.d[1].gelu=0;
        g3.d[2].A=xp; g3.d[2].B=t_wv; g3.d[2].C=vb; g3.d[2].mblks=MR/GBM; g3.d[2].gelu=0;
        gemm_batch<<<dim3(3*(MR/GBM),2),256,0,stream>>>(g3);
        attn_flash<<<dim3(KPOOL/64, BB*HH),256,0,stream>>>(qb, kb, vb, ao);
        GArgs g4; g4.nd = 1;
        g4.d[0].A=ao; g4.d[0].B=t_wo; g4.d[0].C=o2; g4.d[0].mblks=MR/GBM; g4.d[0].gelu=0;
        gemm_batch<<<dim3(MR/GBM,2),256,0,stream>>>(g4);
        ln_kernel<<<MR,256,0,stream>>>(xp, o2, ln_g, ln_b, gatt);
        feat_reduce2<<<dim3(BB,12),256,0,stream>>>(xp, gatt, bi ? vbuf : ubuf);
    }

    cosine_kernel<<<BB,64,0,stream>>>(ubuf, vbuf, out);
}

// Round 4
// 2437.320 us; speedup vs baseline: 9.1038x; 1.3909x over previous
//
#include <hip/hip_runtime.h>
#include <math.h>
#include <stdint.h>

#define LL 2
#define HH 4
#define DHH 64
#define DD 256
#define BB 8
#define NI 8192
#define ND 4096
#define NROW 12288
#define NHOM 12288
#define KPOOL 768
#define EC 65536
#define EI 32768
#define EO 32768
#define EK 8192
#define EHGT (EC+EI+EO+EK)
#define EHOM (EC+EI+EO+EK+NHOM)
#define ENC_NEG_INF 0x007FFFFFu

typedef unsigned short u16;
typedef short bf16x8 __attribute__((ext_vector_type(8)));
typedef float f32x4 __attribute__((ext_vector_type(4)));
typedef unsigned short u16x4 __attribute__((ext_vector_type(4)));

__device__ inline float gelu_f(float x){ return 0.5f*x*(1.f+erff(x*0.70710678118654752f)); }
__device__ inline uint32_t fenc(float x){ uint32_t u=__float_as_uint(x); return (u&0x80000000u)? ~u : (u|0x80000000u); }
__device__ inline float fdec(uint32_t k){ return (k&0x80000000u)? __uint_as_float(k&0x7fffffffu) : __uint_as_float(~k); }
__device__ inline u16 f2b(float x){ uint32_t u=__float_as_uint(x); return (u16)((u + 0x7fffu + ((u>>16)&1u))>>16); }
__device__ inline float b2f(u16 h){ return __uint_as_float(((uint32_t)h)<<16); }

// ---------------- generic fill ----------------
__global__ void fill_u32(uint32_t* p, uint32_t v, int n){
    int i = blockIdx.x*256 + threadIdx.x;
    if(i<n) p[i]=v;
}

// ---------------- activation split-convert: [A | B] -> hi/lo bf16 ----------------
__global__ void cvt_split(const float* __restrict__ A, int nA, const float* __restrict__ B, int nB,
                          u16* __restrict__ oh, u16* __restrict__ ol, int gelu){
    int i = (blockIdx.x*256 + threadIdx.x)*4;
    int tot = nA + nB;
    if(i >= tot) return;
    float4 v = (i < nA) ? *(const float4*)(A + i) : *(const float4*)(B + (i - nA));
    float vv[4] = {v.x, v.y, v.z, v.w};
    u16x4 h4, l4;
    #pragma unroll
    for(int j=0;j<4;j++){
        float x = vv[j];
        if(gelu) x = gelu_f(x);
        u16 h = f2b(x);
        h4[j] = h;
        l4[j] = f2b(x - b2f(h));
    }
    *(u16x4*)(oh + i) = h4;
    *(u16x4*)(ol + i) = l4;
}

// ---------------- weight transpose + split: in[k][n] f32 -> out[n][k] hi/lo bf16 ----------------
struct WCArgs { const float* in[8]; u16* oh[8]; u16* ol[8]; int cnt[8]; int nr; };
__global__ void wcvt_split(WCArgs a){
    int mat = blockIdx.y, ri = 0;
    while(ri < a.nr-1 && mat >= a.cnt[ri]){ mat -= a.cnt[ri]; ri++; }
    const float* in = a.in[ri] + (size_t)mat*65536;
    u16* oh = a.oh[ri] + (size_t)mat*65536;
    u16* ol = a.ol[ri] + (size_t)mat*65536;
    int n = blockIdx.x, k = threadIdx.x;
    float x = in[(size_t)k*DD + n];
    u16 h = f2b(x);
    oh[n*DD + k] = h;
    ol[n*DD + k] = f2b(x - b2f(h));
}

// ---------------- MFMA batched GEMM: C[M,256] = A[M,256] @ B^T  (B stored [N][K]) ----------------
// split-bf16: A ~ Ah+Al, B ~ Bh+Bl; C = Ah*Bh + Ah*Bl + Al*Bh (f32 accum)
struct GDesc { const u16* Ah; const u16* Al; const u16* Bh; const u16* Bl; float* C; int mblks; };
struct GArgs { GDesc d[6]; int nd; };

__global__ __launch_bounds__(256) void gemm_mfma(GArgs ga){
    __shared__ u16 Ah[128][40], Al[128][40], Bh[128][40], Bl[128][40];
    int mb = blockIdx.x, di = 0;
    while(di < ga.nd-1 && mb >= ga.d[di].mblks){ mb -= ga.d[di].mblks; di++; }
    GDesc g = ga.d[di];
    const int m0 = mb*128, n0 = blockIdx.y*128;
    const int tid = threadIdx.x;
    const int lane = tid & 63, wid = tid >> 6;
    const int wm = (wid>>1)*64, wn = (wid&1)*64;
    const int l15 = lane & 15, l4 = lane >> 4;
    const int srow = tid >> 1, scol = (tid & 1)*16;
    const size_t aoff = (size_t)(m0 + srow)*DD + scol;
    const size_t boff = (size_t)(n0 + srow)*DD + scol;
    f32x4 acc[4][4] = {};
    for(int k0=0;k0<DD;k0+=32){
        bf16x8 ah0 = *(const bf16x8*)(g.Ah + aoff + k0);
        bf16x8 ah1 = *(const bf16x8*)(g.Ah + aoff + k0 + 8);
        bf16x8 al0 = *(const bf16x8*)(g.Al + aoff + k0);
        bf16x8 al1 = *(const bf16x8*)(g.Al + aoff + k0 + 8);
        bf16x8 bh0 = *(const bf16x8*)(g.Bh + boff + k0);
        bf16x8 bh1 = *(const bf16x8*)(g.Bh + boff + k0 + 8);
        bf16x8 bl0 = *(const bf16x8*)(g.Bl + boff + k0);
        bf16x8 bl1 = *(const bf16x8*)(g.Bl + boff + k0 + 8);
        __syncthreads();
        *(bf16x8*)&Ah[srow][scol] = ah0; *(bf16x8*)&Ah[srow][scol+8] = ah1;
        *(bf16x8*)&Al[srow][scol] = al0; *(bf16x8*)&Al[srow][scol+8] = al1;
        *(bf16x8*)&Bh[srow][scol] = bh0; *(bf16x8*)&Bh[srow][scol+8] = bh1;
        *(bf16x8*)&Bl[srow][scol] = bl0; *(bf16x8*)&Bl[srow][scol+8] = bl1;
        __syncthreads();
        bf16x8 afh[4], afl[4], bfh[4], bfl[4];
        #pragma unroll
        for(int i=0;i<4;i++){
            afh[i] = *(const bf16x8*)&Ah[wm + i*16 + l15][l4*8];
            afl[i] = *(const bf16x8*)&Al[wm + i*16 + l15][l4*8];
            bfh[i] = *(const bf16x8*)&Bh[wn + i*16 + l15][l4*8];
            bfl[i] = *(const bf16x8*)&Bl[wn + i*16 + l15][l4*8];
        }
        #pragma unroll
        for(int i=0;i<4;i++)
            #pragma unroll
            for(int j=0;j<4;j++){
                acc[i][j] = __builtin_amdgcn_mfma_f32_16x16x32_bf16(afh[i], bfh[j], acc[i][j], 0,0,0);
                acc[i][j] = __builtin_amdgcn_mfma_f32_16x16x32_bf16(afh[i], bfl[j], acc[i][j], 0,0,0);
                acc[i][j] = __builtin_amdgcn_mfma_f32_16x16x32_bf16(afl[i], bfh[j], acc[i][j], 0,0,0);
            }
    }
    #pragma unroll
    for(int i=0;i<4;i++){
        int crow = m0 + wm + i*16 + l4*4;
        #pragma unroll
        for(int j=0;j<4;j++){
            int ccol = n0 + wn + j*16 + l15;
            float* Cp = g.C + (size_t)crow*DD + ccol;
            #pragma unroll
            for(int r=0;r<4;r++) Cp[(size_t)r*DD] = acc[i][j][r];
        }
    }
}

// ---------- combine (f32 temp out): out[d, h*64+f] = sum_k W[d, h*64+k] * R[h,k,f] ----------
__global__ void combine_all(const float* __restrict__ Wk, const float* __restrict__ Wv,
                            const float* __restrict__ Ra, const float* __restrict__ Rm,
                            float* __restrict__ wtk, float* __restrict__ wtv){
    const int st_tab[2][4] = {{0,1,0,0},{0,0,1,0}};
    int combo = blockIdx.y;             // 0..31
    int idx = combo >> 1, kv = combo & 1;
    int r = idx & 3, wb = idx >> 2, dir = wb & 1;
    int st = st_tab[dir][r];
    const float* W = (kv ? Wv : Wk) + (size_t)(wb*2 + st)*65536;
    const float* R = (kv ? Rm : Ra) + (size_t)idx*16384;
    float* o = (kv ? wtv : wtk) + (size_t)idx*65536;
    int d = blockIdx.x, c = threadIdx.x;
    int h = c >> 6, f = c & 63;
    const float* Wrow = W + d*DD + h*64;
    const float* Rh = R + h*4096 + f;
    float s = 0.f;
    #pragma unroll 8
    for(int k=0;k<64;k++) s += Wrow[k]*Rh[k*64];
    o[d*DD + c] = s;
}

// ---------------- CSR build ----------------
__device__ inline void edge_decode(int e, int& r, int& el){
    if(e < EC){ r=0; el=e; }
    else if(e < EC+EI){ r=1; el=e-EC; }
    else if(e < EC+EI+EO){ r=2; el=e-(EC+EI); }
    else { r=3; el=e-(EC+EI+EO); }
}

struct CBArgs {
    const int* row[4]; const int* col[4];
    int dt[4];
    uint32_t* cnt; uint32_t* rowptr; uint32_t* einfo; uint32_t* slot;
};

__global__ void csr_hist(CBArgs a){
    int ge = blockIdx.x*256 + threadIdx.x;
    if(ge >= EHGT) return;
    int r, el; edge_decode(ge, r, el);
    int c = a.col[r][el];
    int dst = a.dt[r] ? (NI + c) : c;
    atomicAdd(&a.cnt[dst], 1u);
}

__global__ __launch_bounds__(1024) void scan_rowptr(uint32_t* cnt, uint32_t* rowptr){
    __shared__ uint32_t part[1024];
    int t = threadIdx.x;
    int base = t*12;
    uint32_t lpre[12];
    uint32_t sum = 0;
    #pragma unroll
    for(int i=0;i<12;i++){
        uint32_t c = cnt[base+i];
        lpre[i] = sum; sum += c;
        cnt[base+i] = 0;
    }
    part[t] = sum;
    __syncthreads();
    for(int offs=1; offs<1024; offs<<=1){
        uint32_t v = (t>=offs) ? part[t-offs] : 0u;
        __syncthreads();
        part[t] += v;
        __syncthreads();
    }
    uint32_t pre = (t==0) ? 0u : part[t-1];
    #pragma unroll
    for(int i=0;i<12;i++) rowptr[base+i] = pre + lpre[i];
    if(t==1023) rowptr[NROW] = part[1023];
}

__global__ void csr_scatter(CBArgs a){
    int ge = blockIdx.x*256 + threadIdx.x;
    if(ge >= EHGT) return;
    int r, el; edge_decode(ge, r, el);
    int c = a.col[r][el];
    int dst = a.dt[r] ? (NI + c) : c;
    int src = a.row[r][el];
    uint32_t p = a.rowptr[dst] + atomicAdd(&a.cnt[dst], 1u);
    a.einfo[p] = (uint32_t)src | ((uint32_t)r << 16);
    a.slot[ge] = p;
}

// ---------------- HGT edge phase ----------------
struct P1Args {
    const int* row[4]; const int* col[4];
    const float* Q[2];
    const float* ka;
    const float* prel;
    const uint32_t* slot;
    float* sc;
    int dt[4];
};

__global__ void hgt_pass1(P1Args a){
    int i = blockIdx.x*256 + threadIdx.x;
    if(i >= EHGT*HH) return;
    int ge = i >> 2, h = i & 3;
    int r, el; edge_decode(ge, r, el);
    int dt = a.dt[r];
    int rn = a.row[r][el], cn = a.col[r][el];
    const float* q  = a.Q[dt] + (size_t)cn*DD + h*64;
    const float* ka = a.ka + (size_t)r*NI*DD + (size_t)rn*DD + h*64;
    float s = 0.f;
    #pragma unroll 8
    for(int d=0;d<64;d++) s += q[d]*ka[d];
    s *= a.prel[r*HH + h]*0.125f;
    a.sc[(size_t)a.slot[ge]*HH + h] = s;
}

// one wave per (dst,h): segment softmax + weighted gather, no atomics
__global__ __launch_bounds__(256) void hgt_rowpass(const uint32_t* __restrict__ rowptr,
                                                   const uint32_t* __restrict__ einfo,
                                                   const float* __restrict__ sc,
                                                   const float* __restrict__ vmb,
                                                   float* __restrict__ agg_i,
                                                   float* __restrict__ agg_d){
    int w = blockIdx.x*4 + (threadIdx.x >> 6);
    int lane = threadIdx.x & 63;
    int rowi = w >> 2, h = w & 3;
    uint32_t p0 = rowptr[rowi], p1 = rowptr[rowi+1];
    float* ag = (rowi < NI) ? (agg_i + (size_t)rowi*DD + h*64)
                            : (agg_d + (size_t)(rowi-NI)*DD + h*64);
    if(p0 == p1){ ag[lane] = 0.f; return; }
    float m = -INFINITY;
    for(uint32_t p = p0+lane; p < p1; p += 64) m = fmaxf(m, sc[(size_t)p*HH + h]);
    #pragma unroll
    for(int s=32;s;s>>=1) m = fmaxf(m, __shfl_xor(m, s));
    float den = 0.f;
    for(uint32_t p = p0+lane; p < p1; p += 64) den += expf(sc[(size_t)p*HH + h] - m);
    #pragma unroll
    for(int s=32;s;s>>=1) den += __shfl_xor(den, s);
    float inv = 1.f/(den + 1e-16f);
    float o = 0.f;
    for(uint32_t p = p0; p < p1; p++){
        uint32_t ei = einfo[p];
        int src = ei & 0xffff, r = ei >> 16;
        float alpha = expf(sc[(size_t)p*HH + h] - m) * inv;
        o += alpha * vmb[((size_t)r*NI + src)*DD + h*64 + lane];
    }
    ag[lane] = o;
}

// epilogue: val = sig(skip[t])*o + (1-sig)*x ; mode0: xacc=0.5*val ; mode1: xnext=relu(xacc+0.5*val)
__global__ void hgt_epilogue(const float* __restrict__ o, const float* __restrict__ x,
                             const float* __restrict__ skip, int t, int n,
                             float* __restrict__ xacc, float* __restrict__ xnext, int mode){
    int i = blockIdx.x*256 + threadIdx.x;
    if(i >= n*DD) return;
    float g = 1.f/(1.f + expf(-skip[t]));
    float val = g*o[i] + (1.f-g)*x[i];
    if(mode==0){
        xacc[i] = 0.5f*val;
    } else {
        float v2 = xacc[i] + 0.5f*val;
        xnext[i] = v2 > 0.f ? v2 : 0.f;
    }
}

// ---------------- pooling ----------------
__global__ void pool_h(const float* __restrict__ x, const float* __restrict__ w,
                       float* __restrict__ h, int n){
    int node = blockIdx.x*4 + (threadIdx.x>>6);
    int lane = threadIdx.x & 63;
    if(node >= n) return;
    const float* xr = x + (size_t)node*DD;
    float s = 0.f;
    for(int j=lane;j<DD;j+=64) s += xr[j]*w[j];
    for(int m=32;m;m>>=1) s += __shfl_xor(s, m);
    if(lane==0) h[node] = s;
}

__global__ void build_hom_edges(const int* __restrict__ ec, const int* __restrict__ ei,
                                const int* __restrict__ eo, const int* __restrict__ ek,
                                int* __restrict__ erow, int* __restrict__ ecol){
    int i = blockIdx.x*256 + threadIdx.x;
    if(i >= EHOM) return;
    int r, c;
    if(i < EC){ r = ec[i]; c = ec[i+EC]; }
    else if(i < EC+EI){ int j=i-EC; r = ei[j]+NI; c = ei[j+EI]; }
    else if(i < EC+EI+EO){ int j=i-(EC+EI); r = eo[j]; c = eo[j+EO]+NI; }
    else if(i < EHGT){ int j=i-(EC+EI+EO); r = ek[j]; c = ek[j+EK]; }
    else { int j=i-EHGT; r = j; c = j; }
    erow[i] = r; ecol[i] = c;
}

__global__ void pool_pass1(const int* __restrict__ row, const int* __restrict__ col,
                           const float* __restrict__ h, const float* __restrict__ att,
                           float* __restrict__ esc, uint32_t* __restrict__ mx){
    int i = blockIdx.x*256 + threadIdx.x;
    if(i>=EHOM) return;
    float e = att[0]*h[row[i]] + att[1]*h[col[i]];
    e = e >= 0.f ? e : 0.2f*e;
    esc[i] = e;
    atomicMax(&mx[col[i]], fenc(e));
}
__global__ void pool_pass2(const int* __restrict__ col, float* __restrict__ esc,
                           const uint32_t* __restrict__ mx, float* __restrict__ den){
    int i = blockIdx.x*256 + threadIdx.x;
    if(i>=EHOM) return;
    float a = expf(esc[i] - fdec(mx[col[i]]));
    esc[i] = a;
    atomicAdd(&den[col[i]], a);
}
__global__ void pool_pass3(const int* __restrict__ row, const int* __restrict__ col,
                           const float* __restrict__ esc, const float* __restrict__ den,
                           const float* __restrict__ h, float* __restrict__ score){
    int i = blockIdx.x*256 + threadIdx.x;
    if(i>=EHOM) return;
    atomicAdd(&score[col[i]], esc[i]/(den[col[i]]+1e-16f) * h[row[i]]);
}

// top-768 of 1536 per graph via bitonic sort (pad to 2048)
__global__ __launch_bounds__(512) void topk_kernel(const float* __restrict__ score,
                                                   const float* __restrict__ bias,
                                                   int* __restrict__ sel_node,
                                                   float* __restrict__ sel_scale){
    __shared__ float skey[2048];
    __shared__ int   sval[2048];
    int b = blockIdx.x;
    float bv = bias[0];
    for(int p=threadIdx.x;p<2048;p+=512){
        if(p<1536){
            int node = (p<1024) ? (b*1024 + p) : (NI + b*512 + (p-1024));
            skey[p] = score[node] + bv;
            sval[p] = node;
        } else {
            skey[p] = -INFINITY;
            sval[p] = -1;
        }
    }
    for(int k=2;k<=2048;k<<=1){
        for(int j=k>>1;j>0;j>>=1){
            __syncthreads();
            for(int i=threadIdx.x;i<2048;i+=512){
                int ixj = i^j;
                if(ixj > i){
                    bool up = ((i & k) == 0);
                    float ki = skey[i], kj = skey[ixj];
                    if((ki < kj) == up){
                        skey[i]=kj; skey[ixj]=ki;
                        int t=sval[i]; sval[i]=sval[ixj]; sval[ixj]=t;
                    }
                }
            }
        }
    }
    __syncthreads();
    for(int j=threadIdx.x;j<KPOOL;j+=512){
        sel_node[b*KPOOL + j] = sval[j];
        sel_scale[b*KPOOL + j] = tanhf(skey[j]);
    }
}

__global__ void gather_xp(const int* __restrict__ sel, const float* __restrict__ scale,
                          const float* __restrict__ xi, const float* __restrict__ xd,
                          float* __restrict__ xp){
    int i = blockIdx.x*256 + threadIdx.x;
    int rowp = i >> 8, c = i & 255;
    int node = sel[rowp];
    float s = scale[rowp];
    float v = (node < NI) ? xi[(size_t)node*DD + c] : xd[(size_t)(node-NI)*DD + c];
    xp[i] = v*s;
}

// ---------------- flash attention: block per (b,h,64-row q tile) ----------------
__global__ __launch_bounds__(256) void attn_flash(const float* __restrict__ Qb,
                                                  const float* __restrict__ Kb,
                                                  const float* __restrict__ Vb,
                                                  float* __restrict__ Ob){
    __shared__ float Qs[64][65];
    __shared__ float Ks[64][65];
    __shared__ float Vs[64][65];
    int bh = blockIdx.y;
    int b = bh >> 2, h = bh & 3;
    int q0 = blockIdx.x * 64;
    int tid = threadIdx.x;
    int tx = tid & 15, ty = tid >> 4;
    #pragma unroll
    for(int k=0;k<4;k++){
        int idx = tid + k*256;
        int r = idx >> 4, c = (idx & 15)*4;
        float4 v = *(const float4*)(Qb + ((size_t)(b*KPOOL + q0 + r))*DD + h*64 + c);
        Qs[r][c]=v.x; Qs[r][c+1]=v.y; Qs[r][c+2]=v.z; Qs[r][c+3]=v.w;
    }
    float m[4], l[4], O[4][4];
    #pragma unroll
    for(int i=0;i<4;i++){ m[i]=-INFINITY; l[i]=0.f;
        #pragma unroll
        for(int j=0;j<4;j++) O[i][j]=0.f; }
    for(int k0=0;k0<KPOOL;k0+=64){
        __syncthreads();
        #pragma unroll
        for(int k=0;k<4;k++){
            int idx = tid + k*256;
            int r = idx >> 4, c = (idx & 15)*4;
            float4 kv = *(const float4*)(Kb + ((size_t)(b*KPOOL + k0 + r))*DD + h*64 + c);
            float4 vv = *(const float4*)(Vb + ((size_t)(b*KPOOL + k0 + r))*DD + h*64 + c);
            Ks[r][c]=kv.x; Ks[r][c+1]=kv.y; Ks[r][c+2]=kv.z; Ks[r][c+3]=kv.w;
            Vs[r][c]=vv.x; Vs[r][c+1]=vv.y; Vs[r][c+2]=vv.z; Vs[r][c+3]=vv.w;
        }
        __syncthreads();
        float s[4][4] = {};
        for(int d=0;d<64;d++){
            float qv[4], kv[4];
            #pragma unroll
            for(int i=0;i<4;i++) qv[i]=Qs[ty*4+i][d];
            #pragma unroll
            for(int j=0;j<4;j++) kv[j]=Ks[tx*4+j][d];
            #pragma unroll
            for(int i=0;i<4;i++)
                #pragma unroll
                for(int j=0;j<4;j++) s[i][j] = fmaf(qv[i], kv[j], s[i][j]);
        }
        float p[4][4];
        #pragma unroll
        for(int i=0;i<4;i++){
            #pragma unroll
            for(int j=0;j<4;j++) s[i][j] *= 0.125f;
            float tm = fmaxf(fmaxf(s[i][0],s[i][1]), fmaxf(s[i][2],s[i][3]));
            #pragma unroll
            for(int msk=8;msk;msk>>=1) tm = fmaxf(tm, __shfl_xor(tm, msk));
            float nm = fmaxf(m[i], tm);
            float esc = expf(m[i]-nm);
            float ps = 0.f;
            #pragma unroll
            for(int j=0;j<4;j++){ p[i][j] = expf(s[i][j]-nm); ps += p[i][j]; }
            #pragma unroll
            for(int msk=8;msk;msk>>=1) ps += __shfl_xor(ps, msk);
            l[i] = l[i]*esc + ps;
            m[i] = nm;
            #pragma unroll
            for(int j=0;j<4;j++) O[i][j] *= esc;
        }
        #pragma unroll
        for(int kb=0;kb<16;kb++){
            int srcl = ((ty&3)<<4) + kb;
            #pragma unroll
            for(int kj=0;kj<4;kj++){
                int kk = kb*4 + kj;
                float vv[4];
                #pragma unroll
                for(int j=0;j<4;j++) vv[j] = Vs[kk][tx*4+j];
                #pragma unroll
                for(int i=0;i<4;i++){
                    float pv = __shfl(p[i][kj], srcl, 64);
                    #pragma unroll
                    for(int j=0;j<4;j++) O[i][j] = fmaf(pv, vv[j], O[i][j]);
                }
            }
        }
    }
    #pragma unroll
    for(int i=0;i<4;i++){
        float inv = 1.f/l[i];
        #pragma unroll
        for(int j=0;j<4;j++)
            Ob[((size_t)(b*KPOOL + q0 + ty*4 + i))*DD + h*64 + tx*4 + j] = O[i][j]*inv;
    }
}

// layernorm row kernel
__global__ __launch_bounds__(256) void ln_kernel(const float* __restrict__ xp, const float* __restrict__ o2,
                                                 const float* __restrict__ lg, const float* __restrict__ lb,
                                                 float* __restrict__ gatt){
    __shared__ float red[256];
    int r = blockIdx.x, c = threadIdx.x;
    float y = xp[(size_t)r*DD + c] + o2[(size_t)r*DD + c];
    red[c] = y; __syncthreads();
    for(int s=128;s;s>>=1){ if(c<s) red[c] += red[c+s]; __syncthreads(); }
    float mu = red[0]*(1.f/DD);
    __syncthreads();
    float d = y - mu;
    red[c] = d*d; __syncthreads();
    for(int s=128;s;s>>=1){ if(c<s) red[c] += red[c+s]; __syncthreads(); }
    float var = red[0]*(1.f/DD);
    gatt[(size_t)r*DD + c] = lg[c]*d/sqrtf(var+1e-5f) + lb[c];
}

__global__ void feat_reduce2(const float* __restrict__ xp, const float* __restrict__ gatt,
                             float* __restrict__ out){
    int b = blockIdx.x, c = threadIdx.x;
    int j0 = blockIdx.y*64;
    float s1=0.f, s2=0.f;
    for(int j=j0;j<j0+64;j++){
        size_t base = ((size_t)(b*KPOOL + j))*DD + c;
        s1 += xp[base];
        s2 += gatt[base];
    }
    atomicAdd(&out[b*512 + c], s1);
    atomicAdd(&out[b*512 + 256 + c], s2);
}

__global__ void cosine_kernel(const float* __restrict__ u, const float* __restrict__ v,
                              float* __restrict__ out){
    int b = blockIdx.x, t = threadIdx.x;
    float du=0.f, nu=0.f, nv=0.f;
    for(int j=t;j<512;j+=64){
        float a = u[b*512+j], bb = v[b*512+j];
        du += a*bb; nu += a*a; nv += bb*bb;
    }
    for(int m=32;m;m>>=1){
        du += __shfl_xor(du,m); nu += __shfl_xor(nu,m); nv += __shfl_xor(nv,m);
    }
    if(t==0) out[b] = du / (fmaxf(sqrtf(nu),1e-8f)*fmaxf(sqrtf(nv),1e-8f));
}

// =======================================================================
extern "C" void kernel_launch(void* const* d_in, const int* in_sizes, int n_in,
                              void* d_out, int out_size, void* d_ws, size_t ws_size,
                              hipStream_t stream){
    (void)in_sizes; (void)n_in; (void)out_size; (void)ws_size;
    const float* hgt_Wk   = (const float*)d_in[12];
    const float* hgt_Wq   = (const float*)d_in[13];
    const float* hgt_Wv   = (const float*)d_in[14];
    const float* hgt_Wo   = (const float*)d_in[15];
    const float* hgt_arel = (const float*)d_in[16];
    const float* hgt_mrel = (const float*)d_in[17];
    const float* hgt_prel = (const float*)d_in[18];
    const float* hgt_skip = (const float*)d_in[19];
    const float* pool_W   = (const float*)d_in[20];
    const float* pool_att = (const float*)d_in[21];
    const float* pool_bias= (const float*)d_in[22];
    const float* t_wq     = (const float*)d_in[23];
    const float* t_wk     = (const float*)d_in[24];
    const float* t_wv     = (const float*)d_in[25];
    const float* t_wo     = (const float*)d_in[26];
    const float* ln_g     = (const float*)d_in[27];
    const float* ln_b     = (const float*)d_in[28];
    float* out = (float*)d_out;

    char* base = (char*)d_ws;
    size_t off = 0;
    auto allocb = [&](size_t nbytes)->void*{
        void* p = (void*)(base + off);
        off += ((nbytes + 255) & ~(size_t)255);
        return p;
    };
    const size_t MAT = 65536;
    // ---- persistent: split-bf16 weights ----
    u16* bwtk_h = (u16*)allocb(16*MAT*2); u16* bwtk_l = (u16*)allocb(16*MAT*2);
    u16* bwtv_h = (u16*)allocb(16*MAT*2); u16* bwtv_l = (u16*)allocb(16*MAT*2);
    u16* bwq_h  = (u16*)allocb(8*MAT*2);  u16* bwq_l  = (u16*)allocb(8*MAT*2);
    u16* bwo_h  = (u16*)allocb(8*MAT*2);  u16* bwo_l  = (u16*)allocb(8*MAT*2);
    u16* btw_h  = (u16*)allocb(4*MAT*2);  u16* btw_l  = (u16*)allocb(4*MAT*2);
    float* ubuf = (float*)allocb(BB*512*4);
    float* vbuf = (float*)allocb(BB*512*4);
    float* xa_i = (float*)allocb((size_t)NI*DD*4);
    float* xa_d = (float*)allocb((size_t)ND*DD*4);
    float* xb_i = (float*)allocb((size_t)NI*DD*4);
    float* xb_d = (float*)allocb((size_t)ND*DD*4);
    size_t region = off;
    // ---- conv scratch ----
    uint32_t* ccnt = (uint32_t*)allocb(NROW*4);
    uint32_t* rowp2[2]; uint32_t* einf2[2]; uint32_t* slot2[2];
    for(int d=0; d<2; d++){
        rowp2[d] = (uint32_t*)allocb((NROW+1)*4);
        einf2[d] = (uint32_t*)allocb((size_t)EHGT*4);
        slot2[d] = (uint32_t*)allocb((size_t)EHGT*4);
    }
    float* q_i  = (float*)allocb((size_t)NI*DD*4);
    float* q_d  = (float*)allocb((size_t)ND*DD*4);
    float* kv   = (float*)allocb((size_t)4*NI*DD*4);   // KA then VM; also combine f32 temp
    float* scb  = (float*)allocb((size_t)EHGT*HH*4);
    float* agg_i = (float*)allocb((size_t)NI*DD*4);
    float* agg_d = (float*)allocb((size_t)ND*DD*4);
    float* xacc_i= (float*)allocb((size_t)NI*DD*4);
    float* xacc_d= (float*)allocb((size_t)ND*DD*4);
    u16* bcur_h = (u16*)allocb((size_t)NROW*DD*2);
    u16* bcur_l = (u16*)allocb((size_t)NROW*DD*2);
    u16* bagg_h = (u16*)allocb((size_t)NROW*DD*2);
    u16* bagg_l = (u16*)allocb((size_t)NROW*DD*2);
    // ---- pooling/transformer overlay ----
    off = region;
    float* hvec = (float*)allocb(NHOM*4);
    int* erow   = (int*)allocb((size_t)EHOM*4);
    int* ecol   = (int*)allocb((size_t)EHOM*4);
    float* esc  = (float*)allocb((size_t)EHOM*4);
    uint32_t* pmk = (uint32_t*)allocb(NHOM*4);
    float* pden = (float*)allocb(NHOM*4);
    float* pscore = (float*)allocb(NHOM*4);
    int* seln   = (int*)allocb(BB*KPOOL*4);
    float* sels = (float*)allocb(BB*KPOOL*4);
    float* xp   = (float*)allocb((size_t)BB*KPOOL*DD*4);
    float* qb   = (float*)allocb((size_t)BB*KPOOL*DD*4);
    float* kb   = (float*)allocb((size_t)BB*KPOOL*DD*4);
    float* vb   = (float*)allocb((size_t)BB*KPOOL*DD*4);
    float* ao   = (float*)allocb((size_t)BB*KPOOL*DD*4);
    float* o2   = (float*)allocb((size_t)BB*KPOOL*DD*4);
    float* gatt = (float*)allocb((size_t)BB*KPOOL*DD*4);
    u16* bxp_h = (u16*)allocb((size_t)BB*KPOOL*DD*2);
    u16* bxp_l = (u16*)allocb((size_t)BB*KPOOL*DD*2);
    u16* bao_h = (u16*)allocb((size_t)BB*KPOOL*DD*2);
    u16* bao_l = (u16*)allocb((size_t)BB*KPOOL*DD*2);

    const int st_tab[2][4] = {{0,1,0,0},{0,0,1,0}};
    const int dt_tab[2][4] = {{0,0,1,0},{0,1,0,0}};
    const int MR = BB*KPOOL;  // 6144

    // zero u/v accumulators
    fill_u32<<<(2*BB*512+255)/256,256,0,stream>>>((uint32_t*)ubuf, 0u, 2*BB*512);
    // fold arel/mrel into Wk/Wv (f32 temp in kv buffer), then transpose+split all weights
    float* wtkF = kv;
    float* wtvF = kv + 16*MAT;
    combine_all<<<dim3(256,32),256,0,stream>>>(hgt_Wk, hgt_Wv, hgt_arel, hgt_mrel, wtkF, wtvF);
    WCArgs wc;
    wc.in[0]=wtkF;   wc.oh[0]=bwtk_h; wc.ol[0]=bwtk_l; wc.cnt[0]=16;
    wc.in[1]=wtvF;   wc.oh[1]=bwtv_h; wc.ol[1]=bwtv_l; wc.cnt[1]=16;
    wc.in[2]=hgt_Wq; wc.oh[2]=bwq_h;  wc.ol[2]=bwq_l;  wc.cnt[2]=8;
    wc.in[3]=hgt_Wo; wc.oh[3]=bwo_h;  wc.ol[3]=bwo_l;  wc.cnt[3]=8;
    wc.in[4]=t_wq;   wc.oh[4]=btw_h;          wc.ol[4]=btw_l;          wc.cnt[4]=1;
    wc.in[5]=t_wk;   wc.oh[5]=btw_h+1*MAT;    wc.ol[5]=btw_l+1*MAT;    wc.cnt[5]=1;
    wc.in[6]=t_wv;   wc.oh[6]=btw_h+2*MAT;    wc.ol[6]=btw_l+2*MAT;    wc.cnt[6]=1;
    wc.in[7]=t_wo;   wc.oh[7]=btw_h+3*MAT;    wc.ol[7]=btw_l+3*MAT;    wc.cnt[7]=1;
    wc.nr = 8;
    wcvt_split<<<dim3(256,52),256,0,stream>>>(wc);

    for(int bi=0;bi<2;bi++){
        int ib = bi*6;
        const float* x_inst = (const float*)d_in[ib+0];
        const float* x_data = (const float*)d_in[ib+1];
        const int* ecp = (const int*)d_in[ib+2];
        const int* eip = (const int*)d_in[ib+3];
        const int* eop = (const int*)d_in[ib+4];
        const int* ekp = (const int*)d_in[ib+5];
        const int* rows_f[4] = {ecp, eip, eop, ekp};
        const int* cols_f[4] = {ecp+EC, eip+EI, eop+EO, ekp+EK};
        const int* rows_r[4] = {ecp+EC, eip+EI, eop+EO, ekp+EK};
        const int* cols_r[4] = {ecp, eip, eop, ekp};

        // ---- CSR build per direction ----
        for(int dir=0; dir<2; dir++){
            CBArgs cb;
            for(int r=0;r<4;r++){
                cb.row[r] = dir ? rows_r[r] : rows_f[r];
                cb.col[r] = dir ? cols_r[r] : cols_f[r];
                cb.dt[r] = dt_tab[dir][r];
            }
            cb.cnt = ccnt; cb.rowptr = rowp2[dir]; cb.einfo = einf2[dir]; cb.slot = slot2[dir];
            fill_u32<<<(NROW+255)/256,256,0,stream>>>(ccnt, 0u, NROW);
            csr_hist<<<(EHGT+255)/256,256,0,stream>>>(cb);
            scan_rowptr<<<1,1024,0,stream>>>(ccnt, rowp2[dir]);
            csr_scatter<<<(EHGT+255)/256,256,0,stream>>>(cb);
        }

        const float* cur_i = x_inst;
        const float* cur_d = x_data;
        for(int l=0;l<LL;l++){
            float* nxt_i = (l==0) ? xa_i : xb_i;
            float* nxt_d = (l==0) ? xa_d : xb_d;
            // split-convert activations once per layer (both dirs share input)
            cvt_split<<<((NROW*DD/4)+255)/256,256,0,stream>>>(cur_i, NI*DD, cur_d, ND*DD, bcur_h, bcur_l, 0);
            for(int dir=0;dir<2;dir++){
                int wb = l*2 + dir;
                const int** rows = dir ? rows_r : rows_f;
                const int** cols = dir ? cols_r : cols_f;

                // --- GEMM batch A: Q(2) + KA(4) ---
                GArgs g1; int nb1 = 0, ndx = 0;
                auto addg = [&](int srctype, const u16* Bh, const u16* Bl, float* Cm, int M){
                    size_t ao = srctype ? (size_t)NI*DD : 0;
                    g1.d[ndx].Ah = bcur_h + ao; g1.d[ndx].Al = bcur_l + ao;
                    g1.d[ndx].Bh = Bh; g1.d[ndx].Bl = Bl; g1.d[ndx].C = Cm;
                    g1.d[ndx].mblks = M/128;
                    nb1 += M/128; ndx++;
                };
                addg(0, bwq_h + (size_t)(wb*2+0)*MAT, bwq_l + (size_t)(wb*2+0)*MAT, q_i, NI);
                addg(1, bwq_h + (size_t)(wb*2+1)*MAT, bwq_l + (size_t)(wb*2+1)*MAT, q_d, ND);
                for(int r=0;r<4;r++){
                    int st = st_tab[dir][r];
                    addg(st, bwtk_h + (size_t)(wb*4+r)*MAT, bwtk_l + (size_t)(wb*4+r)*MAT,
                         kv + (size_t)r*NI*DD, st ? ND : NI);
                }
                g1.nd = ndx;
                gemm_mfma<<<dim3(nb1,2),256,0,stream>>>(g1);

                // --- edge scores into CSR slots (reads kv = KA) ---
                P1Args pa;
                for(int r=0;r<4;r++){
                    pa.row[r] = rows[r]; pa.col[r] = cols[r];
                    pa.dt[r] = dt_tab[dir][r];
                }
                pa.Q[0]=q_i; pa.Q[1]=q_d;
                pa.ka = kv;
                pa.prel = hgt_prel + (size_t)wb*4*HH;
                pa.slot = slot2[dir];
                pa.sc = scb;
                hgt_pass1<<<(EHGT*HH+255)/256,256,0,stream>>>(pa);

                // --- GEMM batch B: VM(4) into kv (KA consumed) ---
                GArgs g2; int nb2 = 0; ndx = 0;
                auto addv = [&](int srctype, const u16* Bh, const u16* Bl, float* Cm, int M){
                    size_t ao = srctype ? (size_t)NI*DD : 0;
                    g2.d[ndx].Ah = bcur_h + ao; g2.d[ndx].Al = bcur_l + ao;
                    g2.d[ndx].Bh = Bh; g2.d[ndx].Bl = Bl; g2.d[ndx].C = Cm;
                    g2.d[ndx].mblks = M/128;
                    nb2 += M/128; ndx++;
                };
                for(int r=0;r<4;r++){
                    int st = st_tab[dir][r];
                    addv(st, bwtv_h + (size_t)(wb*4+r)*MAT, bwtv_l + (size_t)(wb*4+r)*MAT,
                         kv + (size_t)r*NI*DD, st ? ND : NI);
                }
                g2.nd = ndx;
                gemm_mfma<<<dim3(nb2,2),256,0,stream>>>(g2);

                // --- per-(dst,h) softmax + gather ---
                hgt_rowpass<<<NROW,256,0,stream>>>(rowp2[dir], einf2[dir], scb, kv, agg_i, agg_d);

                // --- gelu + split agg, then Wo GEMMs ---
                cvt_split<<<((NROW*DD/4)+255)/256,256,0,stream>>>(agg_i, NI*DD, agg_d, ND*DD, bagg_h, bagg_l, 1);
                GArgs g3; g3.nd = 2;
                g3.d[0].Ah=bagg_h; g3.d[0].Al=bagg_l;
                g3.d[0].Bh=bwo_h + (size_t)(wb*2+0)*MAT; g3.d[0].Bl=bwo_l + (size_t)(wb*2+0)*MAT;
                g3.d[0].C=q_i; g3.d[0].mblks=NI/128;
                g3.d[1].Ah=bagg_h + (size_t)NI*DD; g3.d[1].Al=bagg_l + (size_t)NI*DD;
                g3.d[1].Bh=bwo_h + (size_t)(wb*2+1)*MAT; g3.d[1].Bl=bwo_l + (size_t)(wb*2+1)*MAT;
                g3.d[1].C=q_d; g3.d[1].mblks=ND/128;
                gemm_mfma<<<dim3(NI/128 + ND/128,2),256,0,stream>>>(g3);

                hgt_epilogue<<<(NI*DD+255)/256,256,0,stream>>>(q_i, cur_i, hgt_skip + wb*2, 0, NI, xacc_i, nxt_i, dir);
                hgt_epilogue<<<(ND*DD+255)/256,256,0,stream>>>(q_d, cur_d, hgt_skip + wb*2, 1, ND, xacc_d, nxt_d, dir);
            }
            cur_i = nxt_i;
            cur_d = nxt_d;
        }

        // -------- SAGPooling --------
        pool_h<<<NI/4,256,0,stream>>>(cur_i, pool_W, hvec, NI);
        pool_h<<<ND/4,256,0,stream>>>(cur_d, pool_W, hvec+NI, ND);
        build_hom_edges<<<(EHOM+255)/256,256,0,stream>>>(ecp, eip, eop, ekp, erow, ecol);
        fill_u32<<<(NHOM+255)/256,256,0,stream>>>(pmk, ENC_NEG_INF, NHOM);
        fill_u32<<<(2*NHOM+255)/256,256,0,stream>>>((uint32_t*)pden, 0u, 2*NHOM);
        pool_pass1<<<(EHOM+255)/256,256,0,stream>>>(erow, ecol, hvec, pool_att, esc, pmk);
        pool_pass2<<<(EHOM+255)/256,256,0,stream>>>(ecol, esc, pmk, pden);
        pool_pass3<<<(EHOM+255)/256,256,0,stream>>>(erow, ecol, esc, pden, hvec, pscore);
        topk_kernel<<<BB,512,0,stream>>>(pscore, pool_bias, seln, sels);
        gather_xp<<<BB*KPOOL,256,0,stream>>>(seln, sels, cur_i, cur_d, xp);

        // -------- transformer --------
        cvt_split<<<((MR*DD/4)+255)/256,256,0,stream>>>(xp, MR*DD, nullptr, 0, bxp_h, bxp_l, 0);
        GArgs g4; g4.nd = 3;
        for(int t=0;t<3;t++){
            g4.d[t].Ah=bxp_h; g4.d[t].Al=bxp_l;
            g4.d[t].Bh=btw_h + (size_t)t*MAT; g4.d[t].Bl=btw_l + (size_t)t*MAT;
            g4.d[t].C = (t==0)? qb : (t==1)? kb : vb;
            g4.d[t].mblks = MR/128;
        }
        gemm_mfma<<<dim3(3*(MR/128),2),256,0,stream>>>(g4);
        attn_flash<<<dim3(KPOOL/64, BB*HH),256,0,stream>>>(qb, kb, vb, ao);
        cvt_split<<<((MR*DD/4)+255)/256,256,0,stream>>>(ao, MR*DD, nullptr, 0, bao_h, bao_l, 0);
        GArgs g5; g5.nd = 1;
        g5.d[0].Ah=bao_h; g5.d[0].Al=bao_l;
        g5.d[0].Bh=btw_h + (size_t)3*MAT; g5.d[0].Bl=btw_l + (size_t)3*MAT;
        g5.d[0].C=o2; g5.d[0].mblks=MR/128;
        gemm_mfma<<<dim3(MR/128,2),256,0,stream>>>(g5);
        ln_kernel<<<MR,256,0,stream>>>(xp, o2, ln_g, ln_b, gatt);
        feat_reduce2<<<dim3(BB,12),256,0,stream>>>(xp, gatt, bi ? vbuf : ubuf);
    }

    cosine_kernel<<<BB,64,0,stream>>>(ubuf, vbuf, out);
}

// Round 5
// 1903.746 us; speedup vs baseline: 11.6554x; 1.2803x over previous
//
#include <hip/hip_runtime.h>
#include <math.h>
#include <stdint.h>

#define LL 2
#define HH 4
#define DHH 64
#define DD 256
#define BB 8
#define NI 8192
#define ND 4096
#define NROW 12288
#define NHOM 12288
#define KPOOL 768
#define EC 65536
#define EI 32768
#define EO 32768
#define EK 8192
#define EHGT (EC+EI+EO+EK)
#define EHOM (EC+EI+EO+EK+NHOM)
#define ENC_NEG_INF 0x007FFFFFu

typedef unsigned short u16;
typedef short bf16x8 __attribute__((ext_vector_type(8)));
typedef float f32x4 __attribute__((ext_vector_type(4)));
typedef unsigned short u16x4 __attribute__((ext_vector_type(4)));

__device__ inline float gelu_f(float x){ return 0.5f*x*(1.f+erff(x*0.70710678118654752f)); }
__device__ inline uint32_t fenc(float x){ uint32_t u=__float_as_uint(x); return (u&0x80000000u)? ~u : (u|0x80000000u); }
__device__ inline float fdec(uint32_t k){ return (k&0x80000000u)? __uint_as_float(k&0x7fffffffu) : __uint_as_float(~k); }
__device__ inline u16 f2b(float x){ uint32_t u=__float_as_uint(x); return (u16)((u + 0x7fffu + ((u>>16)&1u))>>16); }
__device__ inline float b2f(u16 h){ return __uint_as_float(((uint32_t)h)<<16); }

// ---------------- generic fill ----------------
__global__ void fill_u32(uint32_t* p, uint32_t v, int n){
    int i = blockIdx.x*256 + threadIdx.x;
    if(i<n) p[i]=v;
}

// ---------------- activation split-convert: [A | B] -> hi/lo bf16 ----------------
__global__ void cvt_split(const float* __restrict__ A, int nA, const float* __restrict__ B, int nB,
                          u16* __restrict__ oh, u16* __restrict__ ol, int gelu){
    int i = (blockIdx.x*256 + threadIdx.x)*4;
    int tot = nA + nB;
    if(i >= tot) return;
    float4 v = (i < nA) ? *(const float4*)(A + i) : *(const float4*)(B + (i - nA));
    float vv[4] = {v.x, v.y, v.z, v.w};
    u16x4 h4, l4;
    #pragma unroll
    for(int j=0;j<4;j++){
        float x = vv[j];
        if(gelu) x = gelu_f(x);
        u16 h = f2b(x);
        h4[j] = h;
        l4[j] = f2b(x - b2f(h));
    }
    *(u16x4*)(oh + i) = h4;
    *(u16x4*)(ol + i) = l4;
}

// ---------------- weight transpose + split ----------------
struct WCArgs { const float* in[8]; u16* oh[8]; u16* ol[8]; int cnt[8]; int nr; };
__global__ void wcvt_split(WCArgs a){
    int mat = blockIdx.y, ri = 0;
    while(ri < a.nr-1 && mat >= a.cnt[ri]){ mat -= a.cnt[ri]; ri++; }
    const float* in = a.in[ri] + (size_t)mat*65536;
    u16* oh = a.oh[ri] + (size_t)mat*65536;
    u16* ol = a.ol[ri] + (size_t)mat*65536;
    int n = blockIdx.x, k = threadIdx.x;
    float x = in[(size_t)k*DD + n];
    u16 h = f2b(x);
    oh[n*DD + k] = h;
    ol[n*DD + k] = f2b(x - b2f(h));
}

// ---------------- MFMA batched GEMM (split-bf16, B stored [N][K]) ----------------
struct GDesc { const u16* Ah; const u16* Al; const u16* Bh; const u16* Bl; float* C; int mblks; };
struct GArgs { GDesc d[6]; int nd; };

__global__ __launch_bounds__(256) void gemm_mfma(GArgs ga){
    __shared__ u16 Ah[128][40], Al[128][40], Bh[128][40], Bl[128][40];
    int mb = blockIdx.x, di = 0;
    while(di < ga.nd-1 && mb >= ga.d[di].mblks){ mb -= ga.d[di].mblks; di++; }
    GDesc g = ga.d[di];
    const int m0 = mb*128, n0 = blockIdx.y*128;
    const int tid = threadIdx.x;
    const int lane = tid & 63, wid = tid >> 6;
    const int wm = (wid>>1)*64, wn = (wid&1)*64;
    const int l15 = lane & 15, l4 = lane >> 4;
    const int srow = tid >> 1, scol = (tid & 1)*16;
    const size_t aoff = (size_t)(m0 + srow)*DD + scol;
    const size_t boff = (size_t)(n0 + srow)*DD + scol;
    f32x4 acc[4][4] = {};
    for(int k0=0;k0<DD;k0+=32){
        bf16x8 ah0 = *(const bf16x8*)(g.Ah + aoff + k0);
        bf16x8 ah1 = *(const bf16x8*)(g.Ah + aoff + k0 + 8);
        bf16x8 al0 = *(const bf16x8*)(g.Al + aoff + k0);
        bf16x8 al1 = *(const bf16x8*)(g.Al + aoff + k0 + 8);
        bf16x8 bh0 = *(const bf16x8*)(g.Bh + boff + k0);
        bf16x8 bh1 = *(const bf16x8*)(g.Bh + boff + k0 + 8);
        bf16x8 bl0 = *(const bf16x8*)(g.Bl + boff + k0);
        bf16x8 bl1 = *(const bf16x8*)(g.Bl + boff + k0 + 8);
        __syncthreads();
        *(bf16x8*)&Ah[srow][scol] = ah0; *(bf16x8*)&Ah[srow][scol+8] = ah1;
        *(bf16x8*)&Al[srow][scol] = al0; *(bf16x8*)&Al[srow][scol+8] = al1;
        *(bf16x8*)&Bh[srow][scol] = bh0; *(bf16x8*)&Bh[srow][scol+8] = bh1;
        *(bf16x8*)&Bl[srow][scol] = bl0; *(bf16x8*)&Bl[srow][scol+8] = bl1;
        __syncthreads();
        bf16x8 afh[4], afl[4], bfh[4], bfl[4];
        #pragma unroll
        for(int i=0;i<4;i++){
            afh[i] = *(const bf16x8*)&Ah[wm + i*16 + l15][l4*8];
            afl[i] = *(const bf16x8*)&Al[wm + i*16 + l15][l4*8];
            bfh[i] = *(const bf16x8*)&Bh[wn + i*16 + l15][l4*8];
            bfl[i] = *(const bf16x8*)&Bl[wn + i*16 + l15][l4*8];
        }
        #pragma unroll
        for(int i=0;i<4;i++)
            #pragma unroll
            for(int j=0;j<4;j++){
                acc[i][j] = __builtin_amdgcn_mfma_f32_16x16x32_bf16(afh[i], bfh[j], acc[i][j], 0,0,0);
                acc[i][j] = __builtin_amdgcn_mfma_f32_16x16x32_bf16(afh[i], bfl[j], acc[i][j], 0,0,0);
                acc[i][j] = __builtin_amdgcn_mfma_f32_16x16x32_bf16(afl[i], bfh[j], acc[i][j], 0,0,0);
            }
    }
    #pragma unroll
    for(int i=0;i<4;i++){
        int crow = m0 + wm + i*16 + l4*4;
        #pragma unroll
        for(int j=0;j<4;j++){
            int ccol = n0 + wn + j*16 + l15;
            float* Cp = g.C + (size_t)crow*DD + ccol;
            #pragma unroll
            for(int r=0;r<4;r++) Cp[(size_t)r*DD] = acc[i][j][r];
        }
    }
}

// ---------- combine ----------
__global__ void combine_all(const float* __restrict__ Wk, const float* __restrict__ Wv,
                            const float* __restrict__ Ra, const float* __restrict__ Rm,
                            float* __restrict__ wtk, float* __restrict__ wtv){
    const int st_tab[2][4] = {{0,1,0,0},{0,0,1,0}};
    int combo = blockIdx.y;
    int idx = combo >> 1, kv = combo & 1;
    int r = idx & 3, wb = idx >> 2, dir = wb & 1;
    int st = st_tab[dir][r];
    const float* W = (kv ? Wv : Wk) + (size_t)(wb*2 + st)*65536;
    const float* R = (kv ? Rm : Ra) + (size_t)idx*16384;
    float* o = (kv ? wtv : wtk) + (size_t)idx*65536;
    int d = blockIdx.x, c = threadIdx.x;
    int h = c >> 6, f = c & 63;
    const float* Wrow = W + d*DD + h*64;
    const float* Rh = R + h*4096 + f;
    float s = 0.f;
    #pragma unroll 8
    for(int k=0;k<64;k++) s += Wrow[k]*Rh[k*64];
    o[d*DD + c] = s;
}

// ---------------- CSR build ----------------
__device__ inline void edge_decode(int e, int& r, int& el){
    if(e < EC){ r=0; el=e; }
    else if(e < EC+EI){ r=1; el=e-EC; }
    else if(e < EC+EI+EO){ r=2; el=e-(EC+EI); }
    else { r=3; el=e-(EC+EI+EO); }
}

struct CBArgs {
    const int* row[4]; const int* col[4];
    int dt[4];
    uint32_t* cnt; uint32_t* rowptr; uint32_t* einfo; uint32_t* slot;
};

__global__ void csr_hist(CBArgs a){
    int ge = blockIdx.x*256 + threadIdx.x;
    if(ge >= EHGT) return;
    int r, el; edge_decode(ge, r, el);
    int c = a.col[r][el];
    int dst = a.dt[r] ? (NI + c) : c;
    atomicAdd(&a.cnt[dst], 1u);
}

__global__ __launch_bounds__(1024) void scan_rowptr(uint32_t* cnt, uint32_t* rowptr){
    __shared__ uint32_t part[1024];
    int t = threadIdx.x;
    int base = t*12;
    uint32_t lpre[12];
    uint32_t sum = 0;
    #pragma unroll
    for(int i=0;i<12;i++){
        uint32_t c = cnt[base+i];
        lpre[i] = sum; sum += c;
        cnt[base+i] = 0;
    }
    part[t] = sum;
    __syncthreads();
    for(int offs=1; offs<1024; offs<<=1){
        uint32_t v = (t>=offs) ? part[t-offs] : 0u;
        __syncthreads();
        part[t] += v;
        __syncthreads();
    }
    uint32_t pre = (t==0) ? 0u : part[t-1];
    #pragma unroll
    for(int i=0;i<12;i++) rowptr[base+i] = pre + lpre[i];
    if(t==1023) rowptr[NROW] = part[1023];
}

__global__ void csr_scatter(CBArgs a){
    int ge = blockIdx.x*256 + threadIdx.x;
    if(ge >= EHGT) return;
    int r, el; edge_decode(ge, r, el);
    int c = a.col[r][el];
    int dst = a.dt[r] ? (NI + c) : c;
    int src = a.row[r][el];
    uint32_t p = a.rowptr[dst] + atomicAdd(&a.cnt[dst], 1u);
    a.einfo[p] = (uint32_t)src | ((uint32_t)r << 16);
    a.slot[ge] = p;
}

// ---------------- HGT edge phase: wave per edge, coalesced ----------------
struct P1Args {
    const int* row[4]; const int* col[4];
    const float* Q[2];
    const float* ka;
    const float* prel;
    const uint32_t* slot;
    float* sc;
    int dt[4];
};

__global__ __launch_bounds__(256) void hgt_pass1(P1Args a){
    int w = blockIdx.x*4 + (threadIdx.x >> 6);   // edge index
    int lane = threadIdx.x & 63;
    if(w >= EHGT) return;
    int r, el; edge_decode(w, r, el);
    int dt = a.dt[r];
    int rn = a.row[r][el], cn = a.col[r][el];
    float4 qv = *(const float4*)(a.Q[dt] + (size_t)cn*DD + lane*4);
    float4 kv = *(const float4*)(a.ka + (size_t)r*NI*DD + (size_t)rn*DD + lane*4);
    float d = qv.x*kv.x + qv.y*kv.y + qv.z*kv.z + qv.w*kv.w;
    d += __shfl_xor(d, 1); d += __shfl_xor(d, 2);
    d += __shfl_xor(d, 4); d += __shfl_xor(d, 8);
    if((lane & 15) == 0){
        int h = lane >> 4;
        a.sc[(size_t)a.slot[w]*HH + h] = d * a.prel[r*HH + h] * 0.125f;
    }
}

// one wave per (dst,h): segment softmax + gather + gelu + split-bf16 out
__global__ __launch_bounds__(256) void hgt_rowpass(const uint32_t* __restrict__ rowptr,
                                                   const uint32_t* __restrict__ einfo,
                                                   const float* __restrict__ sc,
                                                   const float* __restrict__ vmb,
                                                   u16* __restrict__ bagg_h,
                                                   u16* __restrict__ bagg_l){
    int w = blockIdx.x*4 + (threadIdx.x >> 6);
    int lane = threadIdx.x & 63;
    int rowi = w >> 2, h = w & 3;
    uint32_t p0 = rowptr[rowi], p1 = rowptr[rowi+1];
    size_t obase = (rowi < NI) ? ((size_t)rowi*DD + h*64 + lane)
                               : ((size_t)NI*DD + (size_t)(rowi-NI)*DD + h*64 + lane);
    float o = 0.f;
    if(p0 != p1){
        float m = -INFINITY;
        for(uint32_t p = p0+lane; p < p1; p += 64) m = fmaxf(m, sc[(size_t)p*HH + h]);
        #pragma unroll
        for(int s=32;s;s>>=1) m = fmaxf(m, __shfl_xor(m, s));
        float den = 0.f;
        for(uint32_t p = p0+lane; p < p1; p += 64) den += expf(sc[(size_t)p*HH + h] - m);
        #pragma unroll
        for(int s=32;s;s>>=1) den += __shfl_xor(den, s);
        float inv = 1.f/(den + 1e-16f);
        for(uint32_t p = p0; p < p1; p++){
            uint32_t ei = einfo[p];
            int src = ei & 0xffff, r = ei >> 16;
            float alpha = expf(sc[(size_t)p*HH + h] - m) * inv;
            o += alpha * vmb[((size_t)r*NI + src)*DD + h*64 + lane];
        }
    }
    float g = gelu_f(o);
    u16 hh = f2b(g);
    bagg_h[obase] = hh;
    bagg_l[obase] = f2b(g - b2f(hh));
}

// epilogue: val = sig(skip)*o + (1-sig)*x ; mode0: xacc=0.5*val ; mode1: xnext=relu(xacc+0.5*val) + split-bf16 out
__global__ void hgt_epilogue(const float* __restrict__ o, const float* __restrict__ x,
                             const float* __restrict__ skip, int t, int n,
                             float* __restrict__ xacc, float* __restrict__ xnext, int mode,
                             u16* __restrict__ bh, u16* __restrict__ bl){
    int i = blockIdx.x*256 + threadIdx.x;
    if(i >= n*DD) return;
    float g = 1.f/(1.f + expf(-skip[t]));
    float val = g*o[i] + (1.f-g)*x[i];
    if(mode==0){
        xacc[i] = 0.5f*val;
    } else {
        float v2 = xacc[i] + 0.5f*val;
        v2 = v2 > 0.f ? v2 : 0.f;
        xnext[i] = v2;
        u16 hh = f2b(v2);
        bh[i] = hh;
        bl[i] = f2b(v2 - b2f(hh));
    }
}

// ---------------- pooling ----------------
__global__ void pool_h(const float* __restrict__ x, const float* __restrict__ w,
                       float* __restrict__ h, int n){
    int node = blockIdx.x*4 + (threadIdx.x>>6);
    int lane = threadIdx.x & 63;
    if(node >= n) return;
    const float* xr = x + (size_t)node*DD;
    float s = 0.f;
    for(int j=lane;j<DD;j+=64) s += xr[j]*w[j];
    for(int m=32;m;m>>=1) s += __shfl_xor(s, m);
    if(lane==0) h[node] = s;
}

__global__ void build_hom_edges(const int* __restrict__ ec, const int* __restrict__ ei,
                                const int* __restrict__ eo, const int* __restrict__ ek,
                                int* __restrict__ erow, int* __restrict__ ecol){
    int i = blockIdx.x*256 + threadIdx.x;
    if(i >= EHOM) return;
    int r, c;
    if(i < EC){ r = ec[i]; c = ec[i+EC]; }
    else if(i < EC+EI){ int j=i-EC; r = ei[j]+NI; c = ei[j+EI]; }
    else if(i < EC+EI+EO){ int j=i-(EC+EI); r = eo[j]; c = eo[j+EO]+NI; }
    else if(i < EHGT){ int j=i-(EC+EI+EO); r = ek[j]; c = ek[j+EK]; }
    else { int j=i-EHGT; r = j; c = j; }
    erow[i] = r; ecol[i] = c;
}

__global__ void pool_pass1(const int* __restrict__ row, const int* __restrict__ col,
                           const float* __restrict__ h, const float* __restrict__ att,
                           float* __restrict__ esc, uint32_t* __restrict__ mx){
    int i = blockIdx.x*256 + threadIdx.x;
    if(i>=EHOM) return;
    float e = att[0]*h[row[i]] + att[1]*h[col[i]];
    e = e >= 0.f ? e : 0.2f*e;
    esc[i] = e;
    atomicMax(&mx[col[i]], fenc(e));
}
__global__ void pool_pass2(const int* __restrict__ col, float* __restrict__ esc,
                           const uint32_t* __restrict__ mx, float* __restrict__ den){
    int i = blockIdx.x*256 + threadIdx.x;
    if(i>=EHOM) return;
    float a = expf(esc[i] - fdec(mx[col[i]]));
    esc[i] = a;
    atomicAdd(&den[col[i]], a);
}
__global__ void pool_pass3(const int* __restrict__ row, const int* __restrict__ col,
                           const float* __restrict__ esc, const float* __restrict__ den,
                           const float* __restrict__ h, float* __restrict__ score){
    int i = blockIdx.x*256 + threadIdx.x;
    if(i>=EHOM) return;
    atomicAdd(&score[col[i]], esc[i]/(den[col[i]]+1e-16f) * h[row[i]]);
}

// top-768 of 1536 per graph via bitonic sort
__global__ __launch_bounds__(512) void topk_kernel(const float* __restrict__ score,
                                                   const float* __restrict__ bias,
                                                   int* __restrict__ sel_node,
                                                   float* __restrict__ sel_scale){
    __shared__ float skey[2048];
    __shared__ int   sval[2048];
    int b = blockIdx.x;
    float bv = bias[0];
    for(int p=threadIdx.x;p<2048;p+=512){
        if(p<1536){
            int node = (p<1024) ? (b*1024 + p) : (NI + b*512 + (p-1024));
            skey[p] = score[node] + bv;
            sval[p] = node;
        } else {
            skey[p] = -INFINITY;
            sval[p] = -1;
        }
    }
    for(int k=2;k<=2048;k<<=1){
        for(int j=k>>1;j>0;j>>=1){
            __syncthreads();
            for(int i=threadIdx.x;i<2048;i+=512){
                int ixj = i^j;
                if(ixj > i){
                    bool up = ((i & k) == 0);
                    float ki = skey[i], kj = skey[ixj];
                    if((ki < kj) == up){
                        skey[i]=kj; skey[ixj]=ki;
                        int t=sval[i]; sval[i]=sval[ixj]; sval[ixj]=t;
                    }
                }
            }
        }
    }
    __syncthreads();
    for(int j=threadIdx.x;j<KPOOL;j+=512){
        sel_node[b*KPOOL + j] = sval[j];
        sel_scale[b*KPOOL + j] = tanhf(skey[j]);
    }
}

__global__ void gather_xp(const int* __restrict__ sel, const float* __restrict__ scale,
                          const float* __restrict__ xi, const float* __restrict__ xd,
                          float* __restrict__ xp, u16* __restrict__ bh, u16* __restrict__ bl){
    int i = blockIdx.x*256 + threadIdx.x;
    int rowp = i >> 8, c = i & 255;
    int node = sel[rowp];
    float s = scale[rowp];
    float v = (node < NI) ? xi[(size_t)node*DD + c] : xd[(size_t)(node-NI)*DD + c];
    float x = v*s;
    xp[i] = x;
    u16 hh = f2b(x);
    bh[i] = hh;
    bl[i] = f2b(x - b2f(hh));
}

// ---------------- MFMA flash attention: block per (b,h,32 q rows) ----------------
__global__ __launch_bounds__(128) void attn_mfma(const float* __restrict__ Qb,
                                                 const float* __restrict__ Kb,
                                                 const float* __restrict__ Vb,
                                                 u16* __restrict__ aoh,
                                                 u16* __restrict__ aol){
    __shared__ u16 KhS[64*64], KlS[64*64], VtS[64*64];
    char* KhB = (char*)KhS; char* KlB = (char*)KlS; char* VtB = (char*)VtS;
    int bh = blockIdx.y;
    int b = bh >> 2, h = bh & 3;
    int q0 = blockIdx.x * 32;
    int tid = threadIdx.x;
    int lane = tid & 63, w = tid >> 6;
    int l15 = lane & 15, l4 = lane >> 4;
    size_t qrow = (size_t)(b*KPOOL + q0 + w*16 + l15);
    // Q fragments (hi/lo), B-layout: q=l15, dh=(l>>4)*8+j (+32c)
    bf16x8 qh[2], ql[2];
    #pragma unroll
    for(int c=0;c<2;c++){
        const float* qp = Qb + qrow*DD + h*64 + c*32 + l4*8;
        float4 f0 = *(const float4*)qp;
        float4 f1 = *(const float4*)(qp+4);
        float qq[8] = {f0.x,f0.y,f0.z,f0.w,f1.x,f1.y,f1.z,f1.w};
        #pragma unroll
        for(int j=0;j<8;j++){
            u16 hh = f2b(qq[j]);
            qh[c][j] = (short)hh;
            ql[c][j] = (short)f2b(qq[j] - b2f(hh));
        }
    }
    float mreg = -INFINITY, lreg = 0.f;
    f32x4 O[4] = {};
    for(int k0=0;k0<KPOOL;k0+=64){
        __syncthreads();
        {   // stage K hi/lo (swizzled) + V^T (swizzled)
            int row = tid >> 1, half = tid & 1;
            const float* kp = Kb + ((size_t)(b*KPOOL + k0 + row))*DD + h*64 + half*32;
            const float* vp = Vb + ((size_t)(b*KPOOL + k0 + row))*DD + h*64 + half*32;
            int sw = (row&7)<<4;
            #pragma unroll
            for(int g=0; g<4; g++){
                float4 f0 = *(const float4*)(kp + g*8);
                float4 f1 = *(const float4*)(kp + g*8 + 4);
                float kk[8] = {f0.x,f0.y,f0.z,f0.w,f1.x,f1.y,f1.z,f1.w};
                bf16x8 vh, vl;
                #pragma unroll
                for(int j=0;j<8;j++){
                    u16 hh = f2b(kk[j]);
                    vh[j] = (short)hh;
                    vl[j] = (short)f2b(kk[j] - b2f(hh));
                }
                int colb = half*64 + g*16;
                *(bf16x8*)(KhB + row*128 + (colb ^ sw)) = vh;
                *(bf16x8*)(KlB + row*128 + (colb ^ sw)) = vl;
            }
            #pragma unroll
            for(int g=0; g<4; g++){
                float4 f0 = *(const float4*)(vp + g*8);
                float4 f1 = *(const float4*)(vp + g*8 + 4);
                float vv[8] = {f0.x,f0.y,f0.z,f0.w,f1.x,f1.y,f1.z,f1.w};
                #pragma unroll
                for(int j=0;j<8;j++){
                    int dh = half*32 + g*8 + j;
                    *(u16*)(VtB + dh*128 + ((row*2) ^ ((dh&7)<<4))) = f2b(vv[j]);
                }
            }
        }
        __syncthreads();
        // S^T tiles: mfma(A=K, B=Q); C: key=(l>>4)*4+r, q=l15
        f32x4 s[4] = {};
        #pragma unroll
        for(int t=0;t<4;t++){
            int arow = t*16 + l15;
            int sw = (arow&7)<<4;
            const char* bh_ = KhB + arow*128;
            const char* bl_ = KlB + arow*128;
            bf16x8 kh0 = *(const bf16x8*)(bh_ + ((l4*16) ^ sw));
            bf16x8 kh1 = *(const bf16x8*)(bh_ + ((l4*16 + 64) ^ sw));
            bf16x8 kl0 = *(const bf16x8*)(bl_ + ((l4*16) ^ sw));
            bf16x8 kl1 = *(const bf16x8*)(bl_ + ((l4*16 + 64) ^ sw));
            s[t] = __builtin_amdgcn_mfma_f32_16x16x32_bf16(kh0, qh[0], s[t], 0,0,0);
            s[t] = __builtin_amdgcn_mfma_f32_16x16x32_bf16(kh1, qh[1], s[t], 0,0,0);
            s[t] = __builtin_amdgcn_mfma_f32_16x16x32_bf16(kh0, ql[0], s[t], 0,0,0);
            s[t] = __builtin_amdgcn_mfma_f32_16x16x32_bf16(kh1, ql[1], s[t], 0,0,0);
            s[t] = __builtin_amdgcn_mfma_f32_16x16x32_bf16(kl0, qh[0], s[t], 0,0,0);
            s[t] = __builtin_amdgcn_mfma_f32_16x16x32_bf16(kl1, qh[1], s[t], 0,0,0);
        }
        // online softmax (per q = l15; stats reduce across lane-groups)
        float cm = -INFINITY;
        #pragma unroll
        for(int t=0;t<4;t++)
            #pragma unroll
            for(int r=0;r<4;r++){ s[t][r] *= 0.125f; cm = fmaxf(cm, s[t][r]); }
        cm = fmaxf(cm, __shfl_xor(cm,16));
        cm = fmaxf(cm, __shfl_xor(cm,32));
        float nm = fmaxf(mreg, cm);
        float es = expf(mreg - nm);
        float ps = 0.f;
        #pragma unroll
        for(int t=0;t<4;t++)
            #pragma unroll
            for(int r=0;r<4;r++){ float pv = expf(s[t][r] - nm); s[t][r] = pv; ps += pv; }
        ps += __shfl_xor(ps,16);
        ps += __shfl_xor(ps,32);
        lreg = lreg*es + ps;
        mreg = nm;
        #pragma unroll
        for(int d=0;d<4;d++){ O[d][0]*=es; O[d][1]*=es; O[d][2]*=es; O[d][3]*=es; }
        // O^T += mfma(A=V^T, B=P^T) per 32-key chunk
        #pragma unroll
        for(int c32=0;c32<2;c32++){
            bf16x8 pb;
            #pragma unroll
            for(int j=0;j<8;j++){
                int srcl = ((((lane>>4)*2 + (j>>2)) & 3) << 4) | l15;
                float v0 = __shfl(s[c32*2+0][j&3], srcl, 64);
                float v1 = __shfl(s[c32*2+1][j&3], srcl, 64);
                float v = (lane < 32) ? v0 : v1;
                pb[j] = (short)f2b(v);
            }
            #pragma unroll
            for(int dhb=0; dhb<4; dhb++){
                int vrow = dhb*16 + l15;
                bf16x8 va = *(const bf16x8*)(VtB + vrow*128 + ((c32*64 + l4*16) ^ ((vrow&7)<<4)));
                O[dhb] = __builtin_amdgcn_mfma_f32_16x16x32_bf16(va, pb, O[dhb], 0,0,0);
            }
        }
    }
    float inv = 1.f/lreg;
    #pragma unroll
    for(int dhb=0;dhb<4;dhb++)
        #pragma unroll
        for(int r=0;r<4;r++){
            float val = O[dhb][r]*inv;
            size_t o = qrow*DD + h*64 + dhb*16 + l4*4 + r;
            u16 hh = f2b(val);
            aoh[o] = hh;
            aol[o] = f2b(val - b2f(hh));
        }
}

// layernorm row kernel
__global__ __launch_bounds__(256) void ln_kernel(const float* __restrict__ xp, const float* __restrict__ o2,
                                                 const float* __restrict__ lg, const float* __restrict__ lb,
                                                 float* __restrict__ gatt){
    __shared__ float red[256];
    int r = blockIdx.x, c = threadIdx.x;
    float y = xp[(size_t)r*DD + c] + o2[(size_t)r*DD + c];
    red[c] = y; __syncthreads();
    for(int s=128;s;s>>=1){ if(c<s) red[c] += red[c+s]; __syncthreads(); }
    float mu = red[0]*(1.f/DD);
    __syncthreads();
    float d = y - mu;
    red[c] = d*d; __syncthreads();
    for(int s=128;s;s>>=1){ if(c<s) red[c] += red[c+s]; __syncthreads(); }
    float var = red[0]*(1.f/DD);
    gatt[(size_t)r*DD + c] = lg[c]*d/sqrtf(var+1e-5f) + lb[c];
}

__global__ void feat_reduce2(const float* __restrict__ xp, const float* __restrict__ gatt,
                             float* __restrict__ out){
    int b = blockIdx.x, c = threadIdx.x;
    int j0 = blockIdx.y*64;
    float s1=0.f, s2=0.f;
    for(int j=j0;j<j0+64;j++){
        size_t base = ((size_t)(b*KPOOL + j))*DD + c;
        s1 += xp[base];
        s2 += gatt[base];
    }
    atomicAdd(&out[b*512 + c], s1);
    atomicAdd(&out[b*512 + 256 + c], s2);
}

__global__ void cosine_kernel(const float* __restrict__ u, const float* __restrict__ v,
                              float* __restrict__ out){
    int b = blockIdx.x, t = threadIdx.x;
    float du=0.f, nu=0.f, nv=0.f;
    for(int j=t;j<512;j+=64){
        float a = u[b*512+j], bb = v[b*512+j];
        du += a*bb; nu += a*a; nv += bb*bb;
    }
    for(int m=32;m;m>>=1){
        du += __shfl_xor(du,m); nu += __shfl_xor(nu,m); nv += __shfl_xor(nv,m);
    }
    if(t==0) out[b] = du / (fmaxf(sqrtf(nu),1e-8f)*fmaxf(sqrtf(nv),1e-8f));
}

// =======================================================================
extern "C" void kernel_launch(void* const* d_in, const int* in_sizes, int n_in,
                              void* d_out, int out_size, void* d_ws, size_t ws_size,
                              hipStream_t stream){
    (void)in_sizes; (void)n_in; (void)out_size; (void)ws_size;
    const float* hgt_Wk   = (const float*)d_in[12];
    const float* hgt_Wq   = (const float*)d_in[13];
    const float* hgt_Wv   = (const float*)d_in[14];
    const float* hgt_Wo   = (const float*)d_in[15];
    const float* hgt_arel = (const float*)d_in[16];
    const float* hgt_mrel = (const float*)d_in[17];
    const float* hgt_prel = (const float*)d_in[18];
    const float* hgt_skip = (const float*)d_in[19];
    const float* pool_W   = (const float*)d_in[20];
    const float* pool_att = (const float*)d_in[21];
    const float* pool_bias= (const float*)d_in[22];
    const float* t_wq     = (const float*)d_in[23];
    const float* t_wk     = (const float*)d_in[24];
    const float* t_wv     = (const float*)d_in[25];
    const float* t_wo     = (const float*)d_in[26];
    const float* ln_g     = (const float*)d_in[27];
    const float* ln_b     = (const float*)d_in[28];
    float* out = (float*)d_out;

    char* base = (char*)d_ws;
    size_t off = 0;
    auto allocb = [&](size_t nbytes)->void*{
        void* p = (void*)(base + off);
        off += ((nbytes + 255) & ~(size_t)255);
        return p;
    };
    const size_t MAT = 65536;
    // ---- persistent: split-bf16 weights ----
    u16* bwtk_h = (u16*)allocb(16*MAT*2); u16* bwtk_l = (u16*)allocb(16*MAT*2);
    u16* bwtv_h = (u16*)allocb(16*MAT*2); u16* bwtv_l = (u16*)allocb(16*MAT*2);
    u16* bwq_h  = (u16*)allocb(8*MAT*2);  u16* bwq_l  = (u16*)allocb(8*MAT*2);
    u16* bwo_h  = (u16*)allocb(8*MAT*2);  u16* bwo_l  = (u16*)allocb(8*MAT*2);
    u16* btw_h  = (u16*)allocb(4*MAT*2);  u16* btw_l  = (u16*)allocb(4*MAT*2);
    float* ubuf = (float*)allocb(BB*512*4);
    float* vbuf = (float*)allocb(BB*512*4);
    float* xa_i = (float*)allocb((size_t)NI*DD*4);
    float* xa_d = (float*)allocb((size_t)ND*DD*4);
    float* xb_i = (float*)allocb((size_t)NI*DD*4);
    float* xb_d = (float*)allocb((size_t)ND*DD*4);
    size_t region = off;
    // ---- conv scratch ----
    uint32_t* ccnt = (uint32_t*)allocb(NROW*4);
    uint32_t* rowp2[2]; uint32_t* einf2[2]; uint32_t* slot2[2];
    for(int d=0; d<2; d++){
        rowp2[d] = (uint32_t*)allocb((NROW+1)*4);
        einf2[d] = (uint32_t*)allocb((size_t)EHGT*4);
        slot2[d] = (uint32_t*)allocb((size_t)EHGT*4);
    }
    float* q_i  = (float*)allocb((size_t)NI*DD*4);
    float* q_d  = (float*)allocb((size_t)ND*DD*4);
    float* kv   = (float*)allocb((size_t)4*NI*DD*4);
    float* scb  = (float*)allocb((size_t)EHGT*HH*4);
    float* xacc_i= (float*)allocb((size_t)NI*DD*4);
    float* xacc_d= (float*)allocb((size_t)ND*DD*4);
    u16* bcur_h = (u16*)allocb((size_t)NROW*DD*2);
    u16* bcur_l = (u16*)allocb((size_t)NROW*DD*2);
    u16* bagg_h = (u16*)allocb((size_t)NROW*DD*2);
    u16* bagg_l = (u16*)allocb((size_t)NROW*DD*2);
    // ---- pooling/transformer overlay ----
    off = region;
    float* hvec = (float*)allocb(NHOM*4);
    int* erow   = (int*)allocb((size_t)EHOM*4);
    int* ecol   = (int*)allocb((size_t)EHOM*4);
    float* esc  = (float*)allocb((size_t)EHOM*4);
    uint32_t* pmk = (uint32_t*)allocb(NHOM*4);
    float* pden = (float*)allocb(NHOM*4);
    float* pscore = (float*)allocb(NHOM*4);
    int* seln   = (int*)allocb(BB*KPOOL*4);
    float* sels = (float*)allocb(BB*KPOOL*4);
    float* xp   = (float*)allocb((size_t)BB*KPOOL*DD*4);
    float* qb   = (float*)allocb((size_t)BB*KPOOL*DD*4);
    float* kb   = (float*)allocb((size_t)BB*KPOOL*DD*4);
    float* vb   = (float*)allocb((size_t)BB*KPOOL*DD*4);
    float* o2   = (float*)allocb((size_t)BB*KPOOL*DD*4);
    float* gatt = (float*)allocb((size_t)BB*KPOOL*DD*4);
    u16* bxp_h = (u16*)allocb((size_t)BB*KPOOL*DD*2);
    u16* bxp_l = (u16*)allocb((size_t)BB*KPOOL*DD*2);
    u16* bao_h = (u16*)allocb((size_t)BB*KPOOL*DD*2);
    u16* bao_l = (u16*)allocb((size_t)BB*KPOOL*DD*2);

    const int st_tab[2][4] = {{0,1,0,0},{0,0,1,0}};
    const int dt_tab[2][4] = {{0,0,1,0},{0,1,0,0}};
    const int MR = BB*KPOOL;

    fill_u32<<<(2*BB*512+255)/256,256,0,stream>>>((uint32_t*)ubuf, 0u, 2*BB*512);
    float* wtkF = kv;
    float* wtvF = kv + 16*MAT;
    combine_all<<<dim3(256,32),256,0,stream>>>(hgt_Wk, hgt_Wv, hgt_arel, hgt_mrel, wtkF, wtvF);
    WCArgs wc;
    wc.in[0]=wtkF;   wc.oh[0]=bwtk_h; wc.ol[0]=bwtk_l; wc.cnt[0]=16;
    wc.in[1]=wtvF;   wc.oh[1]=bwtv_h; wc.ol[1]=bwtv_l; wc.cnt[1]=16;
    wc.in[2]=hgt_Wq; wc.oh[2]=bwq_h;  wc.ol[2]=bwq_l;  wc.cnt[2]=8;
    wc.in[3]=hgt_Wo; wc.oh[3]=bwo_h;  wc.ol[3]=bwo_l;  wc.cnt[3]=8;
    wc.in[4]=t_wq;   wc.oh[4]=btw_h;          wc.ol[4]=btw_l;          wc.cnt[4]=1;
    wc.in[5]=t_wk;   wc.oh[5]=btw_h+1*MAT;    wc.ol[5]=btw_l+1*MAT;    wc.cnt[5]=1;
    wc.in[6]=t_wv;   wc.oh[6]=btw_h+2*MAT;    wc.ol[6]=btw_l+2*MAT;    wc.cnt[6]=1;
    wc.in[7]=t_wo;   wc.oh[7]=btw_h+3*MAT;    wc.ol[7]=btw_l+3*MAT;    wc.cnt[7]=1;
    wc.nr = 8;
    wcvt_split<<<dim3(256,52),256,0,stream>>>(wc);

    for(int bi=0;bi<2;bi++){
        int ib = bi*6;
        const float* x_inst = (const float*)d_in[ib+0];
        const float* x_data = (const float*)d_in[ib+1];
        const int* ecp = (const int*)d_in[ib+2];
        const int* eip = (const int*)d_in[ib+3];
        const int* eop = (const int*)d_in[ib+4];
        const int* ekp = (const int*)d_in[ib+5];
        const int* rows_f[4] = {ecp, eip, eop, ekp};
        const int* cols_f[4] = {ecp+EC, eip+EI, eop+EO, ekp+EK};
        const int* rows_r[4] = {ecp+EC, eip+EI, eop+EO, ekp+EK};
        const int* cols_r[4] = {ecp, eip, eop, ekp};

        for(int dir=0; dir<2; dir++){
            CBArgs cb;
            for(int r=0;r<4;r++){
                cb.row[r] = dir ? rows_r[r] : rows_f[r];
                cb.col[r] = dir ? cols_r[r] : cols_f[r];
                cb.dt[r] = dt_tab[dir][r];
            }
            cb.cnt = ccnt; cb.rowptr = rowp2[dir]; cb.einfo = einf2[dir]; cb.slot = slot2[dir];
            fill_u32<<<(NROW+255)/256,256,0,stream>>>(ccnt, 0u, NROW);
            csr_hist<<<(EHGT+255)/256,256,0,stream>>>(cb);
            scan_rowptr<<<1,1024,0,stream>>>(ccnt, rowp2[dir]);
            csr_scatter<<<(EHGT+255)/256,256,0,stream>>>(cb);
        }

        const float* cur_i = x_inst;
        const float* cur_d = x_data;
        // initial activation split (layers>0 get it fused into the epilogue)
        cvt_split<<<((NROW*DD/4)+255)/256,256,0,stream>>>(cur_i, NI*DD, cur_d, ND*DD, bcur_h, bcur_l, 0);
        for(int l=0;l<LL;l++){
            float* nxt_i = (l==0) ? xa_i : xb_i;
            float* nxt_d = (l==0) ? xa_d : xb_d;
            for(int dir=0;dir<2;dir++){
                int wb = l*2 + dir;
                const int** rows = dir ? rows_r : rows_f;
                const int** cols = dir ? cols_r : cols_f;

                // --- GEMM batch A: Q(2) + KA(4) ---
                GArgs g1; int nb1 = 0, ndx = 0;
                auto addg = [&](int srctype, const u16* Bh, const u16* Bl, float* Cm, int M){
                    size_t ao = srctype ? (size_t)NI*DD : 0;
                    g1.d[ndx].Ah = bcur_h + ao; g1.d[ndx].Al = bcur_l + ao;
                    g1.d[ndx].Bh = Bh; g1.d[ndx].Bl = Bl; g1.d[ndx].C = Cm;
                    g1.d[ndx].mblks = M/128;
                    nb1 += M/128; ndx++;
                };
                addg(0, bwq_h + (size_t)(wb*2+0)*MAT, bwq_l + (size_t)(wb*2+0)*MAT, q_i, NI);
                addg(1, bwq_h + (size_t)(wb*2+1)*MAT, bwq_l + (size_t)(wb*2+1)*MAT, q_d, ND);
                for(int r=0;r<4;r++){
                    int st = st_tab[dir][r];
                    addg(st, bwtk_h + (size_t)(wb*4+r)*MAT, bwtk_l + (size_t)(wb*4+r)*MAT,
                         kv + (size_t)r*NI*DD, st ? ND : NI);
                }
                g1.nd = ndx;
                gemm_mfma<<<dim3(nb1,2),256,0,stream>>>(g1);

                // --- edge scores (wave per edge, coalesced) ---
                P1Args pa;
                for(int r=0;r<4;r++){
                    pa.row[r] = rows[r]; pa.col[r] = cols[r];
                    pa.dt[r] = dt_tab[dir][r];
                }
                pa.Q[0]=q_i; pa.Q[1]=q_d;
                pa.ka = kv;
                pa.prel = hgt_prel + (size_t)wb*4*HH;
                pa.slot = slot2[dir];
                pa.sc = scb;
                hgt_pass1<<<EHGT/4,256,0,stream>>>(pa);

                // --- GEMM batch B: VM(4) into kv ---
                GArgs g2; int nb2 = 0; ndx = 0;
                auto addv = [&](int srctype, const u16* Bh, const u16* Bl, float* Cm, int M){
                    size_t ao = srctype ? (size_t)NI*DD : 0;
                    g2.d[ndx].Ah = bcur_h + ao; g2.d[ndx].Al = bcur_l + ao;
                    g2.d[ndx].Bh = Bh; g2.d[ndx].Bl = Bl; g2.d[ndx].C = Cm;
                    g2.d[ndx].mblks = M/128;
                    nb2 += M/128; ndx++;
                };
                for(int r=0;r<4;r++){
                    int st = st_tab[dir][r];
                    addv(st, bwtv_h + (size_t)(wb*4+r)*MAT, bwtv_l + (size_t)(wb*4+r)*MAT,
                         kv + (size_t)r*NI*DD, st ? ND : NI);
                }
                g2.nd = ndx;
                gemm_mfma<<<dim3(nb2,2),256,0,stream>>>(g2);

                // --- per-(dst,h) softmax + gather + gelu + split (fused) ---
                hgt_rowpass<<<NROW,256,0,stream>>>(rowp2[dir], einf2[dir], scb, kv, bagg_h, bagg_l);

                // --- Wo GEMMs ---
                GArgs g3; g3.nd = 2;
                g3.d[0].Ah=bagg_h; g3.d[0].Al=bagg_l;
                g3.d[0].Bh=bwo_h + (size_t)(wb*2+0)*MAT; g3.d[0].Bl=bwo_l + (size_t)(wb*2+0)*MAT;
                g3.d[0].C=q_i; g3.d[0].mblks=NI/128;
                g3.d[1].Ah=bagg_h + (size_t)NI*DD; g3.d[1].Al=bagg_l + (size_t)NI*DD;
                g3.d[1].Bh=bwo_h + (size_t)(wb*2+1)*MAT; g3.d[1].Bl=bwo_l + (size_t)(wb*2+1)*MAT;
                g3.d[1].C=q_d; g3.d[1].mblks=ND/128;
                gemm_mfma<<<dim3(NI/128 + ND/128,2),256,0,stream>>>(g3);

                hgt_epilogue<<<(NI*DD+255)/256,256,0,stream>>>(q_i, cur_i, hgt_skip + wb*2, 0, NI,
                    xacc_i, nxt_i, dir, bcur_h, bcur_l);
                hgt_epilogue<<<(ND*DD+255)/256,256,0,stream>>>(q_d, cur_d, hgt_skip + wb*2, 1, ND,
                    xacc_d, nxt_d, dir, bcur_h + (size_t)NI*DD, bcur_l + (size_t)NI*DD);
            }
            cur_i = nxt_i;
            cur_d = nxt_d;
        }

        // -------- SAGPooling --------
        pool_h<<<NI/4,256,0,stream>>>(cur_i, pool_W, hvec, NI);
        pool_h<<<ND/4,256,0,stream>>>(cur_d, pool_W, hvec+NI, ND);
        build_hom_edges<<<(EHOM+255)/256,256,0,stream>>>(ecp, eip, eop, ekp, erow, ecol);
        fill_u32<<<(NHOM+255)/256,256,0,stream>>>(pmk, ENC_NEG_INF, NHOM);
        fill_u32<<<(2*NHOM+255)/256,256,0,stream>>>((uint32_t*)pden, 0u, 2*NHOM);
        pool_pass1<<<(EHOM+255)/256,256,0,stream>>>(erow, ecol, hvec, pool_att, esc, pmk);
        pool_pass2<<<(EHOM+255)/256,256,0,stream>>>(ecol, esc, pmk, pden);
        pool_pass3<<<(EHOM+255)/256,256,0,stream>>>(erow, ecol, esc, pden, hvec, pscore);
        topk_kernel<<<BB,512,0,stream>>>(pscore, pool_bias, seln, sels);
        gather_xp<<<BB*KPOOL,256,0,stream>>>(seln, sels, cur_i, cur_d, xp, bxp_h, bxp_l);

        // -------- transformer --------
        GArgs g4; g4.nd = 3;
        for(int t=0;t<3;t++){
            g4.d[t].Ah=bxp_h; g4.d[t].Al=bxp_l;
            g4.d[t].Bh=btw_h + (size_t)t*MAT; g4.d[t].Bl=btw_l + (size_t)t*MAT;
            g4.d[t].C = (t==0)? qb : (t==1)? kb : vb;
            g4.d[t].mblks = MR/128;
        }
        gemm_mfma<<<dim3(3*(MR/128),2),256,0,stream>>>(g4);
        attn_mfma<<<dim3(KPOOL/32, BB*HH),128,0,stream>>>(qb, kb, vb, bao_h, bao_l);
        GArgs g5; g5.nd = 1;
        g5.d[0].Ah=bao_h; g5.d[0].Al=bao_l;
        g5.d[0].Bh=btw_h + (size_t)3*MAT; g5.d[0].Bl=btw_l + (size_t)3*MAT;
        g5.d[0].C=o2; g5.d[0].mblks=MR/128;
        gemm_mfma<<<dim3(MR/128,2),256,0,stream>>>(g5);
        ln_kernel<<<MR,256,0,stream>>>(xp, o2, ln_g, ln_b, gatt);
        feat_reduce2<<<dim3(BB,12),256,0,stream>>>(xp, gatt, bi ? vbuf : ubuf);
    }

    cosine_kernel<<<BB,64,0,stream>>>(ubuf, vbuf, out);
}